// Round 4
// baseline (2598.312 us; speedup 1.0000x reference)
//
#include <hip/hip_runtime.h>

typedef _Float16 h8 __attribute__((ext_vector_type(8)));
typedef float f32x4 __attribute__((ext_vector_type(4)));

__device__ __forceinline__ float fsigm(float x) {
    return __builtin_amdgcn_rcpf(1.0f + __expf(-x));
}
__device__ __forceinline__ float ftanh(float x) {
    float ax = fabsf(x);
    float e  = __expf(-2.0f * ax);
    float r  = (1.0f - e) * __builtin_amdgcn_rcpf(1.0f + e);
    return copysignf(r, x);
}

// ---------------------------------------------------------------------------
// K1: dist[256][8192] = input[256][512] @ akey[8192][512]^T   (NT GEMM, fp32)
// ---------------------------------------------------------------------------
__global__ __launch_bounds__(256) void k_dist(const float* __restrict__ A,
                                              const float* __restrict__ Bm,
                                              float* __restrict__ C) {
    __shared__ float As[32][68];
    __shared__ float Bs[32][132];
    const int n0 = blockIdx.x * 128;
    const int m0 = blockIdx.y * 64;
    const int tid = threadIdx.x;
    const int tx = tid & 15;
    const int ty = tid >> 4;
    const int lm = tid >> 3;
    const int lk = (tid & 7) * 4;
    float acc[4][8];
#pragma unroll
    for (int i = 0; i < 4; ++i)
#pragma unroll
        for (int j = 0; j < 8; ++j) acc[i][j] = 0.0f;

    for (int kt = 0; kt < 512; kt += 32) {
        __syncthreads();
#pragma unroll
        for (int r = 0; r < 2; ++r) {
            int m = lm + 32 * r;
            float4 v = *(const float4*)&A[(size_t)(m0 + m) * 512 + kt + lk];
            As[lk + 0][m] = v.x; As[lk + 1][m] = v.y;
            As[lk + 2][m] = v.z; As[lk + 3][m] = v.w;
        }
#pragma unroll
        for (int r = 0; r < 4; ++r) {
            int n = lm + 32 * r;
            float4 v = *(const float4*)&Bm[(size_t)(n0 + n) * 512 + kt + lk];
            Bs[lk + 0][n] = v.x; Bs[lk + 1][n] = v.y;
            Bs[lk + 2][n] = v.z; Bs[lk + 3][n] = v.w;
        }
        __syncthreads();
#pragma unroll
        for (int k = 0; k < 32; ++k) {
            float4 a4 = *(const float4*)&As[k][ty * 4];
            float4 b0 = *(const float4*)&Bs[k][tx * 8];
            float4 b1 = *(const float4*)&Bs[k][tx * 8 + 4];
            float av[4] = {a4.x, a4.y, a4.z, a4.w};
            float bv[8] = {b0.x, b0.y, b0.z, b0.w, b1.x, b1.y, b1.z, b1.w};
#pragma unroll
            for (int i = 0; i < 4; ++i)
#pragma unroll
                for (int j = 0; j < 8; ++j)
                    acc[i][j] = fmaf(av[i], bv[j], acc[i][j]);
        }
    }
#pragma unroll
    for (int i = 0; i < 4; ++i) {
        size_t row = (size_t)(m0 + ty * 4 + i) * 8192 + n0 + tx * 8;
        *(float4*)&C[row]     = make_float4(acc[i][0], acc[i][1], acc[i][2], acc[i][3]);
        *(float4*)&C[row + 4] = make_float4(acc[i][4], acc[i][5], acc[i][6], acc[i][7]);
    }
}

// ---------------------------------------------------------------------------
// K2: per-row argmax (first index on ties) -> set 0 -> softmax, in place
// ---------------------------------------------------------------------------
__global__ __launch_bounds__(256) void k_softmax(float* __restrict__ D) {
    __shared__ float row[8192];
    __shared__ float rv[256];
    __shared__ int   ri[256];
    const int b = blockIdx.x, tid = threadIdx.x;
    float* dr = D + (size_t)b * 8192;
    for (int i = tid; i < 2048; i += 256)
        *(float4*)&row[i * 4] = *(const float4*)&dr[i * 4];
    __syncthreads();

    float bv = -INFINITY; int bi = 0x7fffffff;
    for (int i = tid; i < 8192; i += 256) {
        float v = row[i];
        if (v > bv || (v == bv && i < bi)) { bv = v; bi = i; }
    }
    rv[tid] = bv; ri[tid] = bi;
    __syncthreads();
    for (int s = 128; s > 0; s >>= 1) {
        if (tid < s) {
            float ov = rv[tid + s]; int oi = ri[tid + s];
            if (ov > rv[tid] || (ov == rv[tid] && oi < ri[tid])) { rv[tid] = ov; ri[tid] = oi; }
        }
        __syncthreads();
    }
    if (tid == 0) row[ri[0]] = 0.0f;
    __syncthreads();

    float m = -INFINITY;
    for (int i = tid; i < 8192; i += 256) m = fmaxf(m, row[i]);
    rv[tid] = m;
    __syncthreads();
    for (int s = 128; s > 0; s >>= 1) {
        if (tid < s) rv[tid] = fmaxf(rv[tid], rv[tid + s]);
        __syncthreads();
    }
    const float M = rv[0];
    __syncthreads();

    float ssum = 0.0f;
    for (int i = tid; i < 8192; i += 256) {
        float e = __expf(row[i] - M);
        row[i] = e;
        ssum += e;
    }
    rv[tid] = ssum;
    __syncthreads();
    for (int s = 128; s > 0; s >>= 1) {
        if (tid < s) rv[tid] += rv[tid + s];
        __syncthreads();
    }
    const float inv = 1.0f / rv[0];
    for (int i = tid; i < 2048; i += 256) {
        float4 v = *(float4*)&row[i * 4];
        v.x *= inv; v.y *= inv; v.z *= inv; v.w *= inv;
        *(float4*)&dr[i * 4] = v;
    }
}

// ---------------------------------------------------------------------------
// K3: hist[256][544] += a[256][8192] @ aval[8192][544]  (NN GEMM, split-K=8)
// ---------------------------------------------------------------------------
__global__ __launch_bounds__(256) void k_hist(const float* __restrict__ A,
                                              const float* __restrict__ Bm,
                                              float* __restrict__ C) {
    __shared__ float As[32][68];
    __shared__ float Bs[32][68];
    const int n0 = blockIdx.x * 64;
    const int m0 = blockIdx.y * 64;
    const int kz = blockIdx.z;
    const int tid = threadIdx.x;
    const int tx = tid & 15, ty = tid >> 4;
    const int lr = tid >> 3;
    const int lq = (tid & 7) * 4;
    float acc[4][4];
#pragma unroll
    for (int i = 0; i < 4; ++i)
#pragma unroll
        for (int j = 0; j < 4; ++j) acc[i][j] = 0.0f;

    const int k_lo = kz * 1024, k_hi = k_lo + 1024;
    for (int kt = k_lo; kt < k_hi; kt += 32) {
        __syncthreads();
#pragma unroll
        for (int r = 0; r < 2; ++r) {
            int m = lr + 32 * r;
            float4 v = *(const float4*)&A[(size_t)(m0 + m) * 8192 + kt + lq];
            As[lq + 0][m] = v.x; As[lq + 1][m] = v.y;
            As[lq + 2][m] = v.z; As[lq + 3][m] = v.w;
        }
#pragma unroll
        for (int r = 0; r < 2; ++r) {
            int kk = (tid >> 4) + 16 * r;
            int nq = (tid & 15) * 4;
            float4 v = make_float4(0.f, 0.f, 0.f, 0.f);
            if (n0 + nq < 544)
                v = *(const float4*)&Bm[(size_t)(kt + kk) * 544 + n0 + nq];
            *(float4*)&Bs[kk][nq] = v;
        }
        __syncthreads();
#pragma unroll
        for (int k = 0; k < 32; ++k) {
            float4 a4 = *(const float4*)&As[k][ty * 4];
            float4 b4 = *(const float4*)&Bs[k][tx * 4];
            float av[4] = {a4.x, a4.y, a4.z, a4.w};
            float bv[4] = {b4.x, b4.y, b4.z, b4.w};
#pragma unroll
            for (int i = 0; i < 4; ++i)
#pragma unroll
                for (int j = 0; j < 4; ++j)
                    acc[i][j] = fmaf(av[i], bv[j], acc[i][j]);
        }
    }
#pragma unroll
    for (int i = 0; i < 4; ++i)
#pragma unroll
        for (int j = 0; j < 4; ++j) {
            int n = n0 + tx * 4 + j;
            if (n < 544)
                atomicAdd(&C[(size_t)(m0 + ty * 4 + i) * 544 + n], acc[i][j]);
        }
}

// ---------------------------------------------------------------------------
// K4: x[b][t][o] = tanh(b1[o] + W1[o][0]*input[b][t] + sum_j W1[o][1+j]*hist[b][t+j])
// ---------------------------------------------------------------------------
__global__ __launch_bounds__(256) void k_xfeat(const float* __restrict__ inp,
                                               const float* __restrict__ hist,
                                               const float* __restrict__ W1,
                                               const float* __restrict__ b1,
                                               float* __restrict__ X) {
    __shared__ float w[33 * 64];
    __shared__ float bl[64];
    __shared__ float il[128];
    __shared__ float hl[160];
    const int t0 = blockIdx.x * 128;
    const int b  = blockIdx.y;
    const int tid = threadIdx.x;
    for (int idx = tid; idx < 2112; idx += 256) {
        int o = idx / 33, k = idx % 33;
        w[k * 64 + o] = W1[idx];
    }
    if (tid < 64) bl[tid] = b1[tid];
    if (tid < 128) il[tid] = inp[(size_t)b * 512 + t0 + tid];
    for (int i = tid; i < 159; i += 256) hl[i] = hist[(size_t)b * 544 + t0 + i];
    __syncthreads();
    const int o = tid & 63, tq = tid >> 6;
    for (int it = 0; it < 32; ++it) {
        int tl = it * 4 + tq;
        float acc = fmaf(il[tl], w[o], bl[o]);
#pragma unroll
        for (int j = 0; j < 32; ++j)
            acc = fmaf(hl[tl + j], w[(1 + j) * 64 + o], acc);
        X[(size_t)(b * 512 + t0 + tl) * 64 + o] = ftanh(acc);
    }
}

// ---------------------------------------------------------------------------
// K5: pre-gate GEMM (templated K): P[m][g] = bih[g]+bhh[g] + A[row(m)][:K]·Wih[g][:K]
// row(m) = (m>>tcs)*512 + t0 + (m & (TC-1));  A stride = K.  NT, tile 64x128.
// ---------------------------------------------------------------------------
template <int K>
__global__ __launch_bounds__(256) void k_pregemm(const float* __restrict__ A,
                                                 const float* __restrict__ Bm,
                                                 const float* __restrict__ bih,
                                                 const float* __restrict__ bhh,
                                                 float* __restrict__ C,
                                                 int t0, int tcs) {
    __shared__ float As[32][68];
    __shared__ float Bs[32][132];
    const int n0 = blockIdx.x * 128;
    const int m0 = blockIdx.y * 64;
    const int tid = threadIdx.x;
    const int tx = tid & 15;
    const int ty = tid >> 4;
    const int lm = tid >> 3;
    const int lk = (tid & 7) * 4;
    const int tcm = (1 << tcs) - 1;
    float acc[4][8];
#pragma unroll
    for (int i = 0; i < 4; ++i)
#pragma unroll
        for (int j = 0; j < 8; ++j) acc[i][j] = 0.0f;

    for (int kt = 0; kt < K; kt += 32) {
        __syncthreads();
#pragma unroll
        for (int r = 0; r < 2; ++r) {
            int m = m0 + lm + 32 * r;
            size_t arow = (size_t)(m >> tcs) * 512 + t0 + (m & tcm);
            float4 v = *(const float4*)&A[arow * K + kt + lk];
            int ml = lm + 32 * r;
            As[lk + 0][ml] = v.x; As[lk + 1][ml] = v.y;
            As[lk + 2][ml] = v.z; As[lk + 3][ml] = v.w;
        }
#pragma unroll
        for (int r = 0; r < 4; ++r) {
            int n = lm + 32 * r;
            float4 v = *(const float4*)&Bm[(size_t)(n0 + n) * K + kt + lk];
            Bs[lk + 0][n] = v.x; Bs[lk + 1][n] = v.y;
            Bs[lk + 2][n] = v.z; Bs[lk + 3][n] = v.w;
        }
        __syncthreads();
#pragma unroll
        for (int k = 0; k < 32; ++k) {
            float4 a4 = *(const float4*)&As[k][ty * 4];
            float4 b0 = *(const float4*)&Bs[k][tx * 8];
            float4 b1 = *(const float4*)&Bs[k][tx * 8 + 4];
            float av[4] = {a4.x, a4.y, a4.z, a4.w};
            float bv[8] = {b0.x, b0.y, b0.z, b0.w, b1.x, b1.y, b1.z, b1.w};
#pragma unroll
            for (int i = 0; i < 4; ++i)
#pragma unroll
                for (int j = 0; j < 8; ++j)
                    acc[i][j] = fmaf(av[i], bv[j], acc[i][j]);
        }
    }
    float bb[8];
#pragma unroll
    for (int j = 0; j < 8; ++j) {
        int n = n0 + tx * 8 + j;
        bb[j] = bih[n] + bhh[n];
    }
#pragma unroll
    for (int i = 0; i < 4; ++i) {
        size_t row = (size_t)(m0 + ty * 4 + i) * 512 + n0 + tx * 8;
        *(float4*)&C[row]     = make_float4(acc[i][0] + bb[0], acc[i][1] + bb[1],
                                            acc[i][2] + bb[2], acc[i][3] + bb[3]);
        *(float4*)&C[row + 4] = make_float4(acc[i][4] + bb[4], acc[i][5] + bb[5],
                                            acc[i][6] + bb[6], acc[i][7] + bb[7]);
    }
}

// ---------------------------------------------------------------------------
// K6: MFMA LSTM recurrence. 16 blocks x 512 threads; block owns 16 batch rows.
// Per step: gates[16][512] = P_t + h @ Whh^T via mfma_f32_16x16x32_f16 with
// fp16 hi/lo split (3 products: hh, lo*hi, hi*lo -> ~fp32 precision).
// Wave wv owns gates [wv*64, wv*64+64) as 4 N-tiles; weights in 128 VGPRs.
// h kept in LDS as fp16 hi/lo planes (A-frag friendly, padded rows).
// ---------------------------------------------------------------------------
__global__ __launch_bounds__(512, 2) void k_recM(const float* __restrict__ P,
                                                 const float* __restrict__ Whh,
                                                 float* __restrict__ S,
                                                 float* __restrict__ Hout,
                                                 int t0, int TC) {
    __shared__ unsigned int hlhi[16][76];   // 128 halves/row, pad->76 dwords (16B-aligned rows, 2-way banks)
    __shared__ unsigned int hllo[16][76];
    __shared__ float gl[16][516];
    const int b0   = blockIdx.x * 16;
    const int tid  = threadIdx.x;
    const int lane = tid & 63;
    const int wv   = tid >> 6;     // wave 0..7
    const int quad = lane >> 4;    // 0..3
    const int l15  = lane & 15;

    // ---- static B-fragments: Whh[n][k], n=gate (N), k=hidden (K) ----
    h8 bh[4][4], bl[4][4];
#pragma unroll
    for (int tn = 0; tn < 4; ++tn) {
        int n = wv * 64 + tn * 16 + l15;
#pragma unroll
        for (int q = 0; q < 4; ++q) {
            int kb = q * 32 + quad * 8;
            const float* wp = &Whh[(size_t)n * 128 + kb];
            float4 w0 = *(const float4*)wp;
            float4 w1 = *(const float4*)(wp + 4);
            float we[8] = {w0.x, w0.y, w0.z, w0.w, w1.x, w1.y, w1.z, w1.w};
#pragma unroll
            for (int j = 0; j < 8; ++j) {
                _Float16 hi = (_Float16)we[j];
                bh[tn][q][j] = hi;
                bl[tn][q][j] = (_Float16)(we[j] - (float)hi);
            }
        }
    }

    // ---- activation-side ownership: thread -> (m = tid>>5, 4 strided i) ----
    const int am = tid >> 5;
    const int ai = tid & 31;
    float c[4];
    {
        _Float16* rh = (_Float16*)&hlhi[am][0];
        _Float16* rl = (_Float16*)&hllo[am][0];
#pragma unroll
        for (int j = 0; j < 4; ++j) {
            int i = ai + 32 * j;
            float h = S[(size_t)(b0 + am) * 128 + i];
            c[j] = S[32768 + (size_t)(b0 + am) * 128 + i];
            _Float16 hh = (_Float16)h;
            rh[i] = hh;
            rl[i] = (_Float16)(h - (float)hh);
        }
    }
    __syncthreads();

    int nt[4];
#pragma unroll
    for (int tn = 0; tn < 4; ++tn) nt[tn] = wv * 64 + tn * 16 + l15;

    // current-step P fragments (C-layout: row m = quad*4+r)
    float pc[4][4];
#pragma unroll
    for (int tn = 0; tn < 4; ++tn)
#pragma unroll
        for (int r = 0; r < 4; ++r)
            pc[tn][r] = P[(size_t)((b0 + quad * 4 + r) * TC + 0) * 512 + nt[tn]];

    const bool wr = (Hout != nullptr);

    for (int tl = 0; tl < TC; ++tl) {
        // A-fragments of h(t-1) from LDS planes
        h8 ah[4], al[4];
#pragma unroll
        for (int q = 0; q < 4; ++q) {
            ah[q] = *(const h8*)&hlhi[l15][q * 16 + quad * 4];
            al[q] = *(const h8*)&hllo[l15][q * 16 + quad * 4];
        }
        // prefetch next step's P
        float pn[4][4];
        {
            int tl2 = tl + 1;
#pragma unroll
            for (int tn = 0; tn < 4; ++tn)
#pragma unroll
                for (int r = 0; r < 4; ++r)
                    pn[tn][r] = P[(size_t)((b0 + quad * 4 + r) * TC + tl2) * 512 + nt[tn]];
        }
        // MFMA: acc = P + h@W^T (3-way split)
        f32x4 acc[4];
#pragma unroll
        for (int tn = 0; tn < 4; ++tn) {
            acc[tn][0] = pc[tn][0]; acc[tn][1] = pc[tn][1];
            acc[tn][2] = pc[tn][2]; acc[tn][3] = pc[tn][3];
        }
#pragma unroll
        for (int q = 0; q < 4; ++q) {
#pragma unroll
            for (int tn = 0; tn < 4; ++tn) {
                acc[tn] = __builtin_amdgcn_mfma_f32_16x16x32_f16(ah[q], bh[tn][q], acc[tn], 0, 0, 0);
                acc[tn] = __builtin_amdgcn_mfma_f32_16x16x32_f16(al[q], bh[tn][q], acc[tn], 0, 0, 0);
                acc[tn] = __builtin_amdgcn_mfma_f32_16x16x32_f16(ah[q], bl[tn][q], acc[tn], 0, 0, 0);
            }
        }
        // gates -> LDS (C-layout scatter; 2-way banks max)
#pragma unroll
        for (int tn = 0; tn < 4; ++tn)
#pragma unroll
            for (int r = 0; r < 4; ++r)
                gl[quad * 4 + r][nt[tn]] = acc[tn][r];
        __syncthreads();

        // activations: every thread owns 4 (m, i) cells
        {
            _Float16* rh = (_Float16*)&hlhi[am][0];
            _Float16* rl = (_Float16*)&hllo[am][0];
#pragma unroll
            for (int j = 0; j < 4; ++j) {
                int i = ai + 32 * j;
                float pi = gl[am][i];
                float pf = gl[am][128 + i];
                float pg = gl[am][256 + i];
                float po = gl[am][384 + i];
                float iv = fsigm(pi);
                float fv = fsigm(pf);
                float gv = ftanh(pg);
                float ov = fsigm(po);
                c[j] = fv * c[j] + iv * gv;
                float h = ov * ftanh(c[j]);
                _Float16 hh = (_Float16)h;
                rh[i] = hh;
                rl[i] = (_Float16)(h - (float)hh);
                if (wr) Hout[((size_t)(b0 + am) * 512 + t0 + tl) * 128 + i] = h;
                if (tl == TC - 1) {
                    S[(size_t)(b0 + am) * 128 + i] = h;
                    S[32768 + (size_t)(b0 + am) * 128 + i] = c[j];
                }
            }
        }
        __syncthreads();
#pragma unroll
        for (int tn = 0; tn < 4; ++tn)
#pragma unroll
            for (int r = 0; r < 4; ++r)
                pc[tn][r] = pn[tn][r];
    }
}

// ---------------------------------------------------------------------------
// K7: tail head: out = tanh(tanh(h1_last) @ W2^T + b2) @ W3^T + b3
// ---------------------------------------------------------------------------
__global__ __launch_bounds__(64) void k_tail(const float* __restrict__ Hs,
                                             const float* __restrict__ W2,
                                             const float* __restrict__ b2,
                                             const float* __restrict__ W3,
                                             const float* __restrict__ b3,
                                             float* __restrict__ out) {
    __shared__ float last[128], l2s[64];
    const int b = blockIdx.x, tid = threadIdx.x;
    last[tid]      = ftanh(Hs[(size_t)b * 128 + tid]);
    last[tid + 64] = ftanh(Hs[(size_t)b * 128 + 64 + tid]);
    __syncthreads();
    float acc = b2[tid];
#pragma unroll 4
    for (int j = 0; j < 128; ++j) acc = fmaf(W2[(size_t)tid * 128 + j], last[j], acc);
    l2s[tid] = ftanh(acc);
    __syncthreads();
    if (tid < 32) {
        float a2 = b3[tid];
#pragma unroll 4
        for (int o = 0; o < 64; ++o) a2 = fmaf(W3[(size_t)tid * 64 + o], l2s[o], a2);
        out[(size_t)b * 32 + tid] = a2;
    }
}

// ---------------------------------------------------------------------------
extern "C" void kernel_launch(void* const* d_in, const int* in_sizes, int n_in,
                              void* d_out, int out_size, void* d_ws, size_t ws_size,
                              hipStream_t stream) {
    (void)in_sizes; (void)n_in; (void)out_size;
    const float* inp  = (const float*)d_in[0];
    const float* akey = (const float*)d_in[1];
    const float* aval = (const float*)d_in[2];
    const float* W1   = (const float*)d_in[3];
    const float* b1   = (const float*)d_in[4];
    const float* Wih0 = (const float*)d_in[5];
    const float* Whh0 = (const float*)d_in[6];
    const float* bih0 = (const float*)d_in[7];
    const float* bhh0 = (const float*)d_in[8];
    const float* Wih1 = (const float*)d_in[9];
    const float* Whh1 = (const float*)d_in[10];
    const float* bih1 = (const float*)d_in[11];
    const float* bhh1 = (const float*)d_in[12];
    const float* W2   = (const float*)d_in[13];
    const float* b2   = (const float*)d_in[14];
    const float* W3   = (const float*)d_in[15];
    const float* b3   = (const float*)d_in[16];

    float* ws   = (float*)d_ws;
    float* dist = ws;                       // 2,097,152
    float* hist = dist + 2097152;           //   139,264
    float* X    = hist + 139264;            // 8,388,608 + 64 pad
    float* S0   = X + 8388672;              //    65,536 (h then c)
    float* S1   = S0 + 65536;               //    65,536
    float* H0   = S1 + 65536;               // 16,777,216  (h0, [b][512][128])
    float* P0   = H0 + 16777216;            // 256*TC*512 + 1024
    const size_t fixed = (size_t)(P0 - ws);

    // per-TC floats: P0 + P1 = 2*(256*TC*512 + 1024)
    int TC = 32, tcs = 5;
    if ((fixed + 2ull * (131072ull * 128 + 1024)) * 4 <= ws_size)      { TC = 128; tcs = 7; }
    else if ((fixed + 2ull * (131072ull * 64 + 1024)) * 4 <= ws_size)  { TC = 64;  tcs = 6; }
    float* P1 = P0 + (size_t)256 * TC * 512 + 1024;

    k_dist<<<dim3(64, 4), 256, 0, stream>>>(inp, akey, dist);
    k_softmax<<<256, 256, 0, stream>>>(dist);
    hipMemsetAsync(hist, 0, 139264 * 4, stream);
    k_hist<<<dim3(9, 4, 8), 256, 0, stream>>>(dist, aval, hist);
    k_xfeat<<<dim3(4, 256), 256, 0, stream>>>(inp, hist, W1, b1, X);
    hipMemsetAsync(S0, 0, (size_t)2 * 65536 * 4, stream);  // S0+S1 contiguous
    for (int t0 = 0; t0 < 512; t0 += TC) {
        k_pregemm<64><<<dim3(4, 4 * TC), 256, 0, stream>>>(X, Wih0, bih0, bhh0, P0, t0, tcs);
        k_recM<<<16, 512, 0, stream>>>(P0, Whh0, S0, H0, t0, TC);
        k_pregemm<128><<<dim3(4, 4 * TC), 256, 0, stream>>>(H0, Wih1, bih1, bhh1, P1, t0, tcs);
        k_recM<<<16, 512, 0, stream>>>(P1, Whh1, S1, nullptr, t0, TC);
    }
    k_tail<<<256, 64, 0, stream>>>(S1, W2, b2, W3, b3, (float*)d_out);
}

// Round 5
// 2523.705 us; speedup vs baseline: 1.0296x; 1.0296x over previous
//
#include <hip/hip_runtime.h>

typedef _Float16 h8 __attribute__((ext_vector_type(8)));
typedef float f32x4 __attribute__((ext_vector_type(4)));

__device__ __forceinline__ float fsigm(float x) {
    return __builtin_amdgcn_rcpf(1.0f + __expf(-x));
}
__device__ __forceinline__ float ftanh(float x) {
    float ax = fabsf(x);
    float e  = __expf(-2.0f * ax);
    float r  = (1.0f - e) * __builtin_amdgcn_rcpf(1.0f + e);
    return copysignf(r, x);
}
// Workgroup barrier that drains ONLY LDS (lgkmcnt), leaving global loads and
// stores in flight. __syncthreads() would emit s_waitcnt vmcnt(0) and
// serialize every step on LLC/HBM latency.
__device__ __forceinline__ void lds_barrier() {
    asm volatile("s_waitcnt lgkmcnt(0)\n\ts_barrier" ::: "memory");
}

// ---------------------------------------------------------------------------
// K1: dist[256][8192] = input[256][512] @ akey[8192][512]^T   (NT GEMM, fp32)
// ---------------------------------------------------------------------------
__global__ __launch_bounds__(256) void k_dist(const float* __restrict__ A,
                                              const float* __restrict__ Bm,
                                              float* __restrict__ C) {
    __shared__ float As[32][68];
    __shared__ float Bs[32][132];
    const int n0 = blockIdx.x * 128;
    const int m0 = blockIdx.y * 64;
    const int tid = threadIdx.x;
    const int tx = tid & 15;
    const int ty = tid >> 4;
    const int lm = tid >> 3;
    const int lk = (tid & 7) * 4;
    float acc[4][8];
#pragma unroll
    for (int i = 0; i < 4; ++i)
#pragma unroll
        for (int j = 0; j < 8; ++j) acc[i][j] = 0.0f;

    for (int kt = 0; kt < 512; kt += 32) {
        __syncthreads();
#pragma unroll
        for (int r = 0; r < 2; ++r) {
            int m = lm + 32 * r;
            float4 v = *(const float4*)&A[(size_t)(m0 + m) * 512 + kt + lk];
            As[lk + 0][m] = v.x; As[lk + 1][m] = v.y;
            As[lk + 2][m] = v.z; As[lk + 3][m] = v.w;
        }
#pragma unroll
        for (int r = 0; r < 4; ++r) {
            int n = lm + 32 * r;
            float4 v = *(const float4*)&Bm[(size_t)(n0 + n) * 512 + kt + lk];
            Bs[lk + 0][n] = v.x; Bs[lk + 1][n] = v.y;
            Bs[lk + 2][n] = v.z; Bs[lk + 3][n] = v.w;
        }
        __syncthreads();
#pragma unroll
        for (int k = 0; k < 32; ++k) {
            float4 a4 = *(const float4*)&As[k][ty * 4];
            float4 b0 = *(const float4*)&Bs[k][tx * 8];
            float4 b1 = *(const float4*)&Bs[k][tx * 8 + 4];
            float av[4] = {a4.x, a4.y, a4.z, a4.w};
            float bv[8] = {b0.x, b0.y, b0.z, b0.w, b1.x, b1.y, b1.z, b1.w};
#pragma unroll
            for (int i = 0; i < 4; ++i)
#pragma unroll
                for (int j = 0; j < 8; ++j)
                    acc[i][j] = fmaf(av[i], bv[j], acc[i][j]);
        }
    }
#pragma unroll
    for (int i = 0; i < 4; ++i) {
        size_t row = (size_t)(m0 + ty * 4 + i) * 8192 + n0 + tx * 8;
        *(float4*)&C[row]     = make_float4(acc[i][0], acc[i][1], acc[i][2], acc[i][3]);
        *(float4*)&C[row + 4] = make_float4(acc[i][4], acc[i][5], acc[i][6], acc[i][7]);
    }
}

// ---------------------------------------------------------------------------
// K2: per-row argmax (first index on ties) -> set 0 -> softmax, in place
// ---------------------------------------------------------------------------
__global__ __launch_bounds__(256) void k_softmax(float* __restrict__ D) {
    __shared__ float row[8192];
    __shared__ float rv[256];
    __shared__ int   ri[256];
    const int b = blockIdx.x, tid = threadIdx.x;
    float* dr = D + (size_t)b * 8192;
    for (int i = tid; i < 2048; i += 256)
        *(float4*)&row[i * 4] = *(const float4*)&dr[i * 4];
    __syncthreads();

    float bv = -INFINITY; int bi = 0x7fffffff;
    for (int i = tid; i < 8192; i += 256) {
        float v = row[i];
        if (v > bv || (v == bv && i < bi)) { bv = v; bi = i; }
    }
    rv[tid] = bv; ri[tid] = bi;
    __syncthreads();
    for (int s = 128; s > 0; s >>= 1) {
        if (tid < s) {
            float ov = rv[tid + s]; int oi = ri[tid + s];
            if (ov > rv[tid] || (ov == rv[tid] && oi < ri[tid])) { rv[tid] = ov; ri[tid] = oi; }
        }
        __syncthreads();
    }
    if (tid == 0) row[ri[0]] = 0.0f;
    __syncthreads();

    float m = -INFINITY;
    for (int i = tid; i < 8192; i += 256) m = fmaxf(m, row[i]);
    rv[tid] = m;
    __syncthreads();
    for (int s = 128; s > 0; s >>= 1) {
        if (tid < s) rv[tid] = fmaxf(rv[tid], rv[tid + s]);
        __syncthreads();
    }
    const float M = rv[0];
    __syncthreads();

    float ssum = 0.0f;
    for (int i = tid; i < 8192; i += 256) {
        float e = __expf(row[i] - M);
        row[i] = e;
        ssum += e;
    }
    rv[tid] = ssum;
    __syncthreads();
    for (int s = 128; s > 0; s >>= 1) {
        if (tid < s) rv[tid] += rv[tid + s];
        __syncthreads();
    }
    const float inv = 1.0f / rv[0];
    for (int i = tid; i < 2048; i += 256) {
        float4 v = *(float4*)&row[i * 4];
        v.x *= inv; v.y *= inv; v.z *= inv; v.w *= inv;
        *(float4*)&dr[i * 4] = v;
    }
}

// ---------------------------------------------------------------------------
// K3: hist[256][544] += a[256][8192] @ aval[8192][544]  (NN GEMM, split-K=8)
// ---------------------------------------------------------------------------
__global__ __launch_bounds__(256) void k_hist(const float* __restrict__ A,
                                              const float* __restrict__ Bm,
                                              float* __restrict__ C) {
    __shared__ float As[32][68];
    __shared__ float Bs[32][68];
    const int n0 = blockIdx.x * 64;
    const int m0 = blockIdx.y * 64;
    const int kz = blockIdx.z;
    const int tid = threadIdx.x;
    const int tx = tid & 15, ty = tid >> 4;
    const int lr = tid >> 3;
    const int lq = (tid & 7) * 4;
    float acc[4][4];
#pragma unroll
    for (int i = 0; i < 4; ++i)
#pragma unroll
        for (int j = 0; j < 4; ++j) acc[i][j] = 0.0f;

    const int k_lo = kz * 1024, k_hi = k_lo + 1024;
    for (int kt = k_lo; kt < k_hi; kt += 32) {
        __syncthreads();
#pragma unroll
        for (int r = 0; r < 2; ++r) {
            int m = lr + 32 * r;
            float4 v = *(const float4*)&A[(size_t)(m0 + m) * 8192 + kt + lq];
            As[lq + 0][m] = v.x; As[lq + 1][m] = v.y;
            As[lq + 2][m] = v.z; As[lq + 3][m] = v.w;
        }
#pragma unroll
        for (int r = 0; r < 2; ++r) {
            int kk = (tid >> 4) + 16 * r;
            int nq = (tid & 15) * 4;
            float4 v = make_float4(0.f, 0.f, 0.f, 0.f);
            if (n0 + nq < 544)
                v = *(const float4*)&Bm[(size_t)(kt + kk) * 544 + n0 + nq];
            *(float4*)&Bs[kk][nq] = v;
        }
        __syncthreads();
#pragma unroll
        for (int k = 0; k < 32; ++k) {
            float4 a4 = *(const float4*)&As[k][ty * 4];
            float4 b4 = *(const float4*)&Bs[k][tx * 4];
            float av[4] = {a4.x, a4.y, a4.z, a4.w};
            float bv[4] = {b4.x, b4.y, b4.z, b4.w};
#pragma unroll
            for (int i = 0; i < 4; ++i)
#pragma unroll
                for (int j = 0; j < 4; ++j)
                    acc[i][j] = fmaf(av[i], bv[j], acc[i][j]);
        }
    }
#pragma unroll
    for (int i = 0; i < 4; ++i)
#pragma unroll
        for (int j = 0; j < 4; ++j) {
            int n = n0 + tx * 4 + j;
            if (n < 544)
                atomicAdd(&C[(size_t)(m0 + ty * 4 + i) * 544 + n], acc[i][j]);
        }
}

// ---------------------------------------------------------------------------
// K4: x[b][t][o] = tanh(b1[o] + W1[o][0]*input[b][t] + sum_j W1[o][1+j]*hist[b][t+j])
// ---------------------------------------------------------------------------
__global__ __launch_bounds__(256) void k_xfeat(const float* __restrict__ inp,
                                               const float* __restrict__ hist,
                                               const float* __restrict__ W1,
                                               const float* __restrict__ b1,
                                               float* __restrict__ X) {
    __shared__ float w[33 * 64];
    __shared__ float bl[64];
    __shared__ float il[128];
    __shared__ float hl[160];
    const int t0 = blockIdx.x * 128;
    const int b  = blockIdx.y;
    const int tid = threadIdx.x;
    for (int idx = tid; idx < 2112; idx += 256) {
        int o = idx / 33, k = idx % 33;
        w[k * 64 + o] = W1[idx];
    }
    if (tid < 64) bl[tid] = b1[tid];
    if (tid < 128) il[tid] = inp[(size_t)b * 512 + t0 + tid];
    for (int i = tid; i < 159; i += 256) hl[i] = hist[(size_t)b * 544 + t0 + i];
    __syncthreads();
    const int o = tid & 63, tq = tid >> 6;
    for (int it = 0; it < 32; ++it) {
        int tl = it * 4 + tq;
        float acc = fmaf(il[tl], w[o], bl[o]);
#pragma unroll
        for (int j = 0; j < 32; ++j)
            acc = fmaf(hl[tl + j], w[(1 + j) * 64 + o], acc);
        X[(size_t)(b * 512 + t0 + tl) * 64 + o] = ftanh(acc);
    }
}

// ---------------------------------------------------------------------------
// K5: pre-gate GEMM (templated K): P[m][g] = bih[g]+bhh[g] + A[row(m)][:K]·Wih[g][:K]
// row(m) = (m>>tcs)*512 + t0 + (m & (TC-1));  A stride = K.  NT, tile 64x128.
// ---------------------------------------------------------------------------
template <int K>
__global__ __launch_bounds__(256) void k_pregemm(const float* __restrict__ A,
                                                 const float* __restrict__ Bm,
                                                 const float* __restrict__ bih,
                                                 const float* __restrict__ bhh,
                                                 float* __restrict__ C,
                                                 int t0, int tcs) {
    __shared__ float As[32][68];
    __shared__ float Bs[32][132];
    const int n0 = blockIdx.x * 128;
    const int m0 = blockIdx.y * 64;
    const int tid = threadIdx.x;
    const int tx = tid & 15;
    const int ty = tid >> 4;
    const int lm = tid >> 3;
    const int lk = (tid & 7) * 4;
    const int tcm = (1 << tcs) - 1;
    float acc[4][8];
#pragma unroll
    for (int i = 0; i < 4; ++i)
#pragma unroll
        for (int j = 0; j < 8; ++j) acc[i][j] = 0.0f;

    for (int kt = 0; kt < K; kt += 32) {
        __syncthreads();
#pragma unroll
        for (int r = 0; r < 2; ++r) {
            int m = m0 + lm + 32 * r;
            size_t arow = (size_t)(m >> tcs) * 512 + t0 + (m & tcm);
            float4 v = *(const float4*)&A[arow * K + kt + lk];
            int ml = lm + 32 * r;
            As[lk + 0][ml] = v.x; As[lk + 1][ml] = v.y;
            As[lk + 2][ml] = v.z; As[lk + 3][ml] = v.w;
        }
#pragma unroll
        for (int r = 0; r < 4; ++r) {
            int n = lm + 32 * r;
            float4 v = *(const float4*)&Bm[(size_t)(n0 + n) * K + kt + lk];
            Bs[lk + 0][n] = v.x; Bs[lk + 1][n] = v.y;
            Bs[lk + 2][n] = v.z; Bs[lk + 3][n] = v.w;
        }
        __syncthreads();
#pragma unroll
        for (int k = 0; k < 32; ++k) {
            float4 a4 = *(const float4*)&As[k][ty * 4];
            float4 b0 = *(const float4*)&Bs[k][tx * 8];
            float4 b1 = *(const float4*)&Bs[k][tx * 8 + 4];
            float av[4] = {a4.x, a4.y, a4.z, a4.w};
            float bv[8] = {b0.x, b0.y, b0.z, b0.w, b1.x, b1.y, b1.z, b1.w};
#pragma unroll
            for (int i = 0; i < 4; ++i)
#pragma unroll
                for (int j = 0; j < 8; ++j)
                    acc[i][j] = fmaf(av[i], bv[j], acc[i][j]);
        }
    }
    float bb[8];
#pragma unroll
    for (int j = 0; j < 8; ++j) {
        int n = n0 + tx * 8 + j;
        bb[j] = bih[n] + bhh[n];
    }
#pragma unroll
    for (int i = 0; i < 4; ++i) {
        size_t row = (size_t)(m0 + ty * 4 + i) * 512 + n0 + tx * 8;
        *(float4*)&C[row]     = make_float4(acc[i][0] + bb[0], acc[i][1] + bb[1],
                                            acc[i][2] + bb[2], acc[i][3] + bb[3]);
        *(float4*)&C[row + 4] = make_float4(acc[i][4] + bb[4], acc[i][5] + bb[5],
                                            acc[i][6] + bb[6], acc[i][7] + bb[7]);
    }
}

// ---------------------------------------------------------------------------
// K6: MFMA LSTM recurrence. 16 blocks x 512 threads; block owns 16 batch rows.
// gates[16][512] = P_t + h @ Whh^T via mfma_f32_16x16x32_f16, fp16 hi/lo split
// (3 products). Barriers are LDS-only (lds_barrier) so the per-step P
// prefetch stays in flight across the step — no vmcnt(0) drain.
// h planes: stride-64-dword rows + XOR swizzle (d ^ ((m&7)<<2)) -> aligned
// b128 reads, 2-lane bank groups (free).
// ---------------------------------------------------------------------------
__global__ __launch_bounds__(512, 2) void k_recM(const float* __restrict__ P,
                                                 const float* __restrict__ Whh,
                                                 float* __restrict__ S,
                                                 float* __restrict__ Hout,
                                                 int t0, int TC) {
    __shared__ unsigned int hlhi[16 * 64];   // fp16 planes, swizzled
    __shared__ unsigned int hllo[16 * 64];
    __shared__ float gl[16][516];
    const int b0   = blockIdx.x * 16;
    const int tid  = threadIdx.x;
    const int lane = tid & 63;
    const int wv   = tid >> 6;     // wave 0..7
    const int quad = lane >> 4;    // 0..3
    const int l15  = lane & 15;

    // ---- static B-fragments: Whh[n][k] ----
    h8 bh[4][4], bl[4][4];
#pragma unroll
    for (int tn = 0; tn < 4; ++tn) {
        int n = wv * 64 + tn * 16 + l15;
#pragma unroll
        for (int q = 0; q < 4; ++q) {
            int kb = q * 32 + quad * 8;
            const float* wp = &Whh[(size_t)n * 128 + kb];
            float4 w0 = *(const float4*)wp;
            float4 w1 = *(const float4*)(wp + 4);
            float we[8] = {w0.x, w0.y, w0.z, w0.w, w1.x, w1.y, w1.z, w1.w};
#pragma unroll
            for (int j = 0; j < 8; ++j) {
                _Float16 hi = (_Float16)we[j];
                bh[tn][q][j] = hi;
                bl[tn][q][j] = (_Float16)(we[j] - (float)hi);
            }
        }
    }

    // ---- activation-side ownership: thread -> (m = tid>>5, 4 strided i) ----
    const int am = tid >> 5;
    const unsigned swa = (unsigned)(am & 7) << 2;
    float c[4];
#pragma unroll
    for (int j = 0; j < 4; ++j) {
        int i = (tid & 31) + 32 * j;
        float h = S[(size_t)(b0 + am) * 128 + i];
        c[j] = S[32768 + (size_t)(b0 + am) * 128 + i];
        _Float16 hh = (_Float16)h;
        int pd = (i >> 1) ^ swa;
        ((_Float16*)&hlhi[am * 64 + pd])[i & 1] = hh;
        ((_Float16*)&hllo[am * 64 + pd])[i & 1] = (_Float16)(h - (float)hh);
    }
    lds_barrier();

    int nt[4];
#pragma unroll
    for (int tn = 0; tn < 4; ++tn) nt[tn] = wv * 64 + tn * 16 + l15;
    const unsigned swr = (unsigned)(l15 & 7) << 2;

    // current-step P fragments (C-layout: row m = quad*4+r)
    float pc[4][4];
#pragma unroll
    for (int tn = 0; tn < 4; ++tn)
#pragma unroll
        for (int r = 0; r < 4; ++r)
            pc[tn][r] = P[(size_t)((b0 + quad * 4 + r) * TC + 0) * 512 + nt[tn]];

    const bool wr = (Hout != nullptr);

    for (int tl = 0; tl < TC; ++tl) {
        // prefetch next step's P first (max distance to consumption; barriers
        // below do NOT drain vmcnt)
        float pn[4][4];
        {
            int tl2 = tl + 1;
#pragma unroll
            for (int tn = 0; tn < 4; ++tn)
#pragma unroll
                for (int r = 0; r < 4; ++r)
                    pn[tn][r] = P[(size_t)((b0 + quad * 4 + r) * TC + tl2) * 512 + nt[tn]];
        }
        // A-fragments of h(t-1) from swizzled LDS planes
        h8 ah[4], al[4];
#pragma unroll
        for (int q = 0; q < 4; ++q) {
            unsigned d = (unsigned)(16 * q + 4 * quad) ^ swr;
            ah[q] = *(const h8*)&hlhi[l15 * 64 + d];
            al[q] = *(const h8*)&hllo[l15 * 64 + d];
        }
        // MFMA: acc = P + h@W^T (3-way split)
        f32x4 acc[4];
#pragma unroll
        for (int tn = 0; tn < 4; ++tn) {
            acc[tn][0] = pc[tn][0]; acc[tn][1] = pc[tn][1];
            acc[tn][2] = pc[tn][2]; acc[tn][3] = pc[tn][3];
        }
#pragma unroll
        for (int q = 0; q < 4; ++q) {
#pragma unroll
            for (int tn = 0; tn < 4; ++tn) {
                acc[tn] = __builtin_amdgcn_mfma_f32_16x16x32_f16(ah[q], bh[tn][q], acc[tn], 0, 0, 0);
                acc[tn] = __builtin_amdgcn_mfma_f32_16x16x32_f16(al[q], bh[tn][q], acc[tn], 0, 0, 0);
                acc[tn] = __builtin_amdgcn_mfma_f32_16x16x32_f16(ah[q], bl[tn][q], acc[tn], 0, 0, 0);
            }
        }
        // gates -> LDS (C-layout scatter; 2-way banks max)
#pragma unroll
        for (int tn = 0; tn < 4; ++tn)
#pragma unroll
            for (int r = 0; r < 4; ++r)
                gl[quad * 4 + r][nt[tn]] = acc[tn][r];
        lds_barrier();

        // activations: every thread owns 4 (m, i) cells
#pragma unroll
        for (int j = 0; j < 4; ++j) {
            int i = (tid & 31) + 32 * j;
            float pi = gl[am][i];
            float pf = gl[am][128 + i];
            float pg = gl[am][256 + i];
            float po = gl[am][384 + i];
            float iv = fsigm(pi);
            float fv = fsigm(pf);
            float gv = ftanh(pg);
            float ov = fsigm(po);
            c[j] = fv * c[j] + iv * gv;
            float h = ov * ftanh(c[j]);
            _Float16 hh = (_Float16)h;
            int pd = (i >> 1) ^ swa;
            ((_Float16*)&hlhi[am * 64 + pd])[i & 1] = hh;
            ((_Float16*)&hllo[am * 64 + pd])[i & 1] = (_Float16)(h - (float)hh);
            if (wr) Hout[((size_t)(b0 + am) * 512 + t0 + tl) * 128 + i] = h;
            if (tl == TC - 1) {
                S[(size_t)(b0 + am) * 128 + i] = h;
                S[32768 + (size_t)(b0 + am) * 128 + i] = c[j];
            }
        }
        lds_barrier();
#pragma unroll
        for (int tn = 0; tn < 4; ++tn)
#pragma unroll
            for (int r = 0; r < 4; ++r)
                pc[tn][r] = pn[tn][r];
    }
}

// ---------------------------------------------------------------------------
// K7: tail head: out = tanh(tanh(h1_last) @ W2^T + b2) @ W3^T + b3
// ---------------------------------------------------------------------------
__global__ __launch_bounds__(64) void k_tail(const float* __restrict__ Hs,
                                             const float* __restrict__ W2,
                                             const float* __restrict__ b2,
                                             const float* __restrict__ W3,
                                             const float* __restrict__ b3,
                                             float* __restrict__ out) {
    __shared__ float last[128], l2s[64];
    const int b = blockIdx.x, tid = threadIdx.x;
    last[tid]      = ftanh(Hs[(size_t)b * 128 + tid]);
    last[tid + 64] = ftanh(Hs[(size_t)b * 128 + 64 + tid]);
    __syncthreads();
    float acc = b2[tid];
#pragma unroll 4
    for (int j = 0; j < 128; ++j) acc = fmaf(W2[(size_t)tid * 128 + j], last[j], acc);
    l2s[tid] = ftanh(acc);
    __syncthreads();
    if (tid < 32) {
        float a2 = b3[tid];
#pragma unroll 4
        for (int o = 0; o < 64; ++o) a2 = fmaf(W3[(size_t)tid * 64 + o], l2s[o], a2);
        out[(size_t)b * 32 + tid] = a2;
    }
}

// ---------------------------------------------------------------------------
extern "C" void kernel_launch(void* const* d_in, const int* in_sizes, int n_in,
                              void* d_out, int out_size, void* d_ws, size_t ws_size,
                              hipStream_t stream) {
    (void)in_sizes; (void)n_in; (void)out_size;
    const float* inp  = (const float*)d_in[0];
    const float* akey = (const float*)d_in[1];
    const float* aval = (const float*)d_in[2];
    const float* W1   = (const float*)d_in[3];
    const float* b1   = (const float*)d_in[4];
    const float* Wih0 = (const float*)d_in[5];
    const float* Whh0 = (const float*)d_in[6];
    const float* bih0 = (const float*)d_in[7];
    const float* bhh0 = (const float*)d_in[8];
    const float* Wih1 = (const float*)d_in[9];
    const float* Whh1 = (const float*)d_in[10];
    const float* bih1 = (const float*)d_in[11];
    const float* bhh1 = (const float*)d_in[12];
    const float* W2   = (const float*)d_in[13];
    const float* b2   = (const float*)d_in[14];
    const float* W3   = (const float*)d_in[15];
    const float* b3   = (const float*)d_in[16];

    float* ws   = (float*)d_ws;
    float* dist = ws;                       // 2,097,152
    float* hist = dist + 2097152;           //   139,264
    float* X    = hist + 139264;            // 8,388,608 + 64 pad
    float* S0   = X + 8388672;              //    65,536 (h then c)
    float* S1   = S0 + 65536;               //    65,536
    float* H0   = S1 + 65536;               // 16,777,216  (h0, [b][512][128])
    float* P0   = H0 + 16777216;            // 256*TC*512 + 1024
    const size_t fixed = (size_t)(P0 - ws);

    // per-TC floats: P0 + P1 = 2*(256*TC*512 + 1024)
    int TC = 32, tcs = 5;
    if ((fixed + 2ull * (131072ull * 128 + 1024)) * 4 <= ws_size)      { TC = 128; tcs = 7; }
    else if ((fixed + 2ull * (131072ull * 64 + 1024)) * 4 <= ws_size)  { TC = 64;  tcs = 6; }
    float* P1 = P0 + (size_t)256 * TC * 512 + 1024;

    k_dist<<<dim3(64, 4), 256, 0, stream>>>(inp, akey, dist);
    k_softmax<<<256, 256, 0, stream>>>(dist);
    hipMemsetAsync(hist, 0, 139264 * 4, stream);
    k_hist<<<dim3(9, 4, 8), 256, 0, stream>>>(dist, aval, hist);
    k_xfeat<<<dim3(4, 256), 256, 0, stream>>>(inp, hist, W1, b1, X);
    hipMemsetAsync(S0, 0, (size_t)2 * 65536 * 4, stream);  // S0+S1 contiguous
    for (int t0 = 0; t0 < 512; t0 += TC) {
        k_pregemm<64><<<dim3(4, 4 * TC), 256, 0, stream>>>(X, Wih0, bih0, bhh0, P0, t0, tcs);
        k_recM<<<16, 512, 0, stream>>>(P0, Whh0, S0, H0, t0, TC);
        k_pregemm<128><<<dim3(4, 4 * TC), 256, 0, stream>>>(H0, Wih1, bih1, bhh1, P1, t0, tcs);
        k_recM<<<16, 512, 0, stream>>>(P1, Whh1, S1, nullptr, t0, TC);
    }
    k_tail<<<256, 64, 0, stream>>>(S1, W2, b2, W3, b3, (float*)d_out);
}

// Round 6
// 2182.872 us; speedup vs baseline: 1.1903x; 1.1561x over previous
//
#include <hip/hip_runtime.h>

typedef _Float16 h8 __attribute__((ext_vector_type(8)));
typedef float f32x4 __attribute__((ext_vector_type(4)));

__device__ __forceinline__ float fsigm(float x) {
    return __builtin_amdgcn_rcpf(1.0f + __expf(-x));
}
__device__ __forceinline__ float ftanh(float x) {
    float ax = fabsf(x);
    float e  = __expf(-2.0f * ax);
    float r  = (1.0f - e) * __builtin_amdgcn_rcpf(1.0f + e);
    return copysignf(r, x);
}
// LDS-only barrier: drains lgkmcnt, leaves global loads/stores in flight
// (__syncthreads would add s_waitcnt vmcnt(0) -> LLC latency every step).
__device__ __forceinline__ void lds_barrier() {
    asm volatile("s_waitcnt lgkmcnt(0)\n\ts_barrier" ::: "memory");
}

// ---------------------------------------------------------------------------
// K1: dist[256][8192] = input[256][512] @ akey[8192][512]^T   (NT GEMM, fp32)
// ---------------------------------------------------------------------------
__global__ __launch_bounds__(256) void k_dist(const float* __restrict__ A,
                                              const float* __restrict__ Bm,
                                              float* __restrict__ C) {
    __shared__ float As[32][68];
    __shared__ float Bs[32][132];
    const int n0 = blockIdx.x * 128;
    const int m0 = blockIdx.y * 64;
    const int tid = threadIdx.x;
    const int tx = tid & 15;
    const int ty = tid >> 4;
    const int lm = tid >> 3;
    const int lk = (tid & 7) * 4;
    float acc[4][8];
#pragma unroll
    for (int i = 0; i < 4; ++i)
#pragma unroll
        for (int j = 0; j < 8; ++j) acc[i][j] = 0.0f;

    for (int kt = 0; kt < 512; kt += 32) {
        __syncthreads();
#pragma unroll
        for (int r = 0; r < 2; ++r) {
            int m = lm + 32 * r;
            float4 v = *(const float4*)&A[(size_t)(m0 + m) * 512 + kt + lk];
            As[lk + 0][m] = v.x; As[lk + 1][m] = v.y;
            As[lk + 2][m] = v.z; As[lk + 3][m] = v.w;
        }
#pragma unroll
        for (int r = 0; r < 4; ++r) {
            int n = lm + 32 * r;
            float4 v = *(const float4*)&Bm[(size_t)(n0 + n) * 512 + kt + lk];
            Bs[lk + 0][n] = v.x; Bs[lk + 1][n] = v.y;
            Bs[lk + 2][n] = v.z; Bs[lk + 3][n] = v.w;
        }
        __syncthreads();
#pragma unroll
        for (int k = 0; k < 32; ++k) {
            float4 a4 = *(const float4*)&As[k][ty * 4];
            float4 b0 = *(const float4*)&Bs[k][tx * 8];
            float4 b1 = *(const float4*)&Bs[k][tx * 8 + 4];
            float av[4] = {a4.x, a4.y, a4.z, a4.w};
            float bv[8] = {b0.x, b0.y, b0.z, b0.w, b1.x, b1.y, b1.z, b1.w};
#pragma unroll
            for (int i = 0; i < 4; ++i)
#pragma unroll
                for (int j = 0; j < 8; ++j)
                    acc[i][j] = fmaf(av[i], bv[j], acc[i][j]);
        }
    }
#pragma unroll
    for (int i = 0; i < 4; ++i) {
        size_t row = (size_t)(m0 + ty * 4 + i) * 8192 + n0 + tx * 8;
        *(float4*)&C[row]     = make_float4(acc[i][0], acc[i][1], acc[i][2], acc[i][3]);
        *(float4*)&C[row + 4] = make_float4(acc[i][4], acc[i][5], acc[i][6], acc[i][7]);
    }
}

// ---------------------------------------------------------------------------
// K2: per-row argmax (first index on ties) -> set 0 -> softmax, in place
// ---------------------------------------------------------------------------
__global__ __launch_bounds__(256) void k_softmax(float* __restrict__ D) {
    __shared__ float row[8192];
    __shared__ float rv[256];
    __shared__ int   ri[256];
    const int b = blockIdx.x, tid = threadIdx.x;
    float* dr = D + (size_t)b * 8192;
    for (int i = tid; i < 2048; i += 256)
        *(float4*)&row[i * 4] = *(const float4*)&dr[i * 4];
    __syncthreads();

    float bv = -INFINITY; int bi = 0x7fffffff;
    for (int i = tid; i < 8192; i += 256) {
        float v = row[i];
        if (v > bv || (v == bv && i < bi)) { bv = v; bi = i; }
    }
    rv[tid] = bv; ri[tid] = bi;
    __syncthreads();
    for (int s = 128; s > 0; s >>= 1) {
        if (tid < s) {
            float ov = rv[tid + s]; int oi = ri[tid + s];
            if (ov > rv[tid] || (ov == rv[tid] && oi < ri[tid])) { rv[tid] = ov; ri[tid] = oi; }
        }
        __syncthreads();
    }
    if (tid == 0) row[ri[0]] = 0.0f;
    __syncthreads();

    float m = -INFINITY;
    for (int i = tid; i < 8192; i += 256) m = fmaxf(m, row[i]);
    rv[tid] = m;
    __syncthreads();
    for (int s = 128; s > 0; s >>= 1) {
        if (tid < s) rv[tid] = fmaxf(rv[tid], rv[tid + s]);
        __syncthreads();
    }
    const float M = rv[0];
    __syncthreads();

    float ssum = 0.0f;
    for (int i = tid; i < 8192; i += 256) {
        float e = __expf(row[i] - M);
        row[i] = e;
        ssum += e;
    }
    rv[tid] = ssum;
    __syncthreads();
    for (int s = 128; s > 0; s >>= 1) {
        if (tid < s) rv[tid] += rv[tid + s];
        __syncthreads();
    }
    const float inv = 1.0f / rv[0];
    for (int i = tid; i < 2048; i += 256) {
        float4 v = *(float4*)&row[i * 4];
        v.x *= inv; v.y *= inv; v.z *= inv; v.w *= inv;
        *(float4*)&dr[i * 4] = v;
    }
}

// ---------------------------------------------------------------------------
// K3: hist[256][544] += a[256][8192] @ aval[8192][544]  (NN GEMM, split-K=8)
// ---------------------------------------------------------------------------
__global__ __launch_bounds__(256) void k_hist(const float* __restrict__ A,
                                              const float* __restrict__ Bm,
                                              float* __restrict__ C) {
    __shared__ float As[32][68];
    __shared__ float Bs[32][68];
    const int n0 = blockIdx.x * 64;
    const int m0 = blockIdx.y * 64;
    const int kz = blockIdx.z;
    const int tid = threadIdx.x;
    const int tx = tid & 15, ty = tid >> 4;
    const int lr = tid >> 3;
    const int lq = (tid & 7) * 4;
    float acc[4][4];
#pragma unroll
    for (int i = 0; i < 4; ++i)
#pragma unroll
        for (int j = 0; j < 4; ++j) acc[i][j] = 0.0f;

    const int k_lo = kz * 1024, k_hi = k_lo + 1024;
    for (int kt = k_lo; kt < k_hi; kt += 32) {
        __syncthreads();
#pragma unroll
        for (int r = 0; r < 2; ++r) {
            int m = lr + 32 * r;
            float4 v = *(const float4*)&A[(size_t)(m0 + m) * 8192 + kt + lq];
            As[lq + 0][m] = v.x; As[lq + 1][m] = v.y;
            As[lq + 2][m] = v.z; As[lq + 3][m] = v.w;
        }
#pragma unroll
        for (int r = 0; r < 2; ++r) {
            int kk = (tid >> 4) + 16 * r;
            int nq = (tid & 15) * 4;
            float4 v = make_float4(0.f, 0.f, 0.f, 0.f);
            if (n0 + nq < 544)
                v = *(const float4*)&Bm[(size_t)(kt + kk) * 544 + n0 + nq];
            *(float4*)&Bs[kk][nq] = v;
        }
        __syncthreads();
#pragma unroll
        for (int k = 0; k < 32; ++k) {
            float4 a4 = *(const float4*)&As[k][ty * 4];
            float4 b4 = *(const float4*)&Bs[k][tx * 4];
            float av[4] = {a4.x, a4.y, a4.z, a4.w};
            float bv[4] = {b4.x, b4.y, b4.z, b4.w};
#pragma unroll
            for (int i = 0; i < 4; ++i)
#pragma unroll
                for (int j = 0; j < 4; ++j)
                    acc[i][j] = fmaf(av[i], bv[j], acc[i][j]);
        }
    }
#pragma unroll
    for (int i = 0; i < 4; ++i)
#pragma unroll
        for (int j = 0; j < 4; ++j) {
            int n = n0 + tx * 4 + j;
            if (n < 544)
                atomicAdd(&C[(size_t)(m0 + ty * 4 + i) * 544 + n], acc[i][j]);
        }
}

// ---------------------------------------------------------------------------
// K4: x[b][t][o] = tanh(b1[o] + W1[o][0]*input[b][t] + sum_j W1[o][1+j]*hist[b][t+j])
// ---------------------------------------------------------------------------
__global__ __launch_bounds__(256) void k_xfeat(const float* __restrict__ inp,
                                               const float* __restrict__ hist,
                                               const float* __restrict__ W1,
                                               const float* __restrict__ b1,
                                               float* __restrict__ X) {
    __shared__ float w[33 * 64];
    __shared__ float bl[64];
    __shared__ float il[128];
    __shared__ float hl[160];
    const int t0 = blockIdx.x * 128;
    const int b  = blockIdx.y;
    const int tid = threadIdx.x;
    for (int idx = tid; idx < 2112; idx += 256) {
        int o = idx / 33, k = idx % 33;
        w[k * 64 + o] = W1[idx];
    }
    if (tid < 64) bl[tid] = b1[tid];
    if (tid < 128) il[tid] = inp[(size_t)b * 512 + t0 + tid];
    for (int i = tid; i < 159; i += 256) hl[i] = hist[(size_t)b * 544 + t0 + i];
    __syncthreads();
    const int o = tid & 63, tq = tid >> 6;
    for (int it = 0; it < 32; ++it) {
        int tl = it * 4 + tq;
        float acc = fmaf(il[tl], w[o], bl[o]);
#pragma unroll
        for (int j = 0; j < 32; ++j)
            acc = fmaf(hl[tl + j], w[(1 + j) * 64 + o], acc);
        X[(size_t)(b * 512 + t0 + tl) * 64 + o] = ftanh(acc);
    }
}

// ---------------------------------------------------------------------------
// K5: pre-gate GEMM (templated K): P[m][g] = bih[g]+bhh[g] + A[row(m)][:K]·Wih[g][:K]
// row(m) = (m>>tcs)*512 + t0 + (m & (TC-1));  A stride = K.  NT, tile 64x128.
// ---------------------------------------------------------------------------
template <int K>
__global__ __launch_bounds__(256) void k_pregemm(const float* __restrict__ A,
                                                 const float* __restrict__ Bm,
                                                 const float* __restrict__ bih,
                                                 const float* __restrict__ bhh,
                                                 float* __restrict__ C,
                                                 int t0, int tcs) {
    __shared__ float As[32][68];
    __shared__ float Bs[32][132];
    const int n0 = blockIdx.x * 128;
    const int m0 = blockIdx.y * 64;
    const int tid = threadIdx.x;
    const int tx = tid & 15;
    const int ty = tid >> 4;
    const int lm = tid >> 3;
    const int lk = (tid & 7) * 4;
    const int tcm = (1 << tcs) - 1;
    float acc[4][8];
#pragma unroll
    for (int i = 0; i < 4; ++i)
#pragma unroll
        for (int j = 0; j < 8; ++j) acc[i][j] = 0.0f;

    for (int kt = 0; kt < K; kt += 32) {
        __syncthreads();
#pragma unroll
        for (int r = 0; r < 2; ++r) {
            int m = m0 + lm + 32 * r;
            size_t arow = (size_t)(m >> tcs) * 512 + t0 + (m & tcm);
            float4 v = *(const float4*)&A[arow * K + kt + lk];
            int ml = lm + 32 * r;
            As[lk + 0][ml] = v.x; As[lk + 1][ml] = v.y;
            As[lk + 2][ml] = v.z; As[lk + 3][ml] = v.w;
        }
#pragma unroll
        for (int r = 0; r < 4; ++r) {
            int n = lm + 32 * r;
            float4 v = *(const float4*)&Bm[(size_t)(n0 + n) * K + kt + lk];
            Bs[lk + 0][n] = v.x; Bs[lk + 1][n] = v.y;
            Bs[lk + 2][n] = v.z; Bs[lk + 3][n] = v.w;
        }
        __syncthreads();
#pragma unroll
        for (int k = 0; k < 32; ++k) {
            float4 a4 = *(const float4*)&As[k][ty * 4];
            float4 b0 = *(const float4*)&Bs[k][tx * 8];
            float4 b1 = *(const float4*)&Bs[k][tx * 8 + 4];
            float av[4] = {a4.x, a4.y, a4.z, a4.w};
            float bv[8] = {b0.x, b0.y, b0.z, b0.w, b1.x, b1.y, b1.z, b1.w};
#pragma unroll
            for (int i = 0; i < 4; ++i)
#pragma unroll
                for (int j = 0; j < 8; ++j)
                    acc[i][j] = fmaf(av[i], bv[j], acc[i][j]);
        }
    }
    float bb[8];
#pragma unroll
    for (int j = 0; j < 8; ++j) {
        int n = n0 + tx * 8 + j;
        bb[j] = bih[n] + bhh[n];
    }
#pragma unroll
    for (int i = 0; i < 4; ++i) {
        size_t row = (size_t)(m0 + ty * 4 + i) * 512 + n0 + tx * 8;
        *(float4*)&C[row]     = make_float4(acc[i][0] + bb[0], acc[i][1] + bb[1],
                                            acc[i][2] + bb[2], acc[i][3] + bb[3]);
        *(float4*)&C[row + 4] = make_float4(acc[i][4] + bb[4], acc[i][5] + bb[5],
                                            acc[i][6] + bb[6], acc[i][7] + bb[7]);
    }
}

// ---------------------------------------------------------------------------
// K6: MFMA LSTM recurrence, lane-local gates. 16 blocks x 512 threads.
// Wave wv owns N-tiles n = g*128 + wv*16 + l15 (g=0..3 -> i,f,g,o): all four
// gate pre-activations of cell (m=quad*4+r, hidden=wv*16+l15) land in ONE
// lane's acc[g][r] -> activations run in-register (no gate LDS round-trip,
// one lgkm-only barrier/step). h crosses waves via double-buffered fp16
// hi/lo LDS planes (stride 72 dwords: b128 reads at the 8/bank floor).
// P loads: 32-bit invariant voffset + per-step uniform base, prefetched
// one step ahead (never drained by the barrier).
// ---------------------------------------------------------------------------
__global__ __launch_bounds__(512, 2) void k_recM(const float* __restrict__ P,
                                                 const float* __restrict__ Whh,
                                                 float* __restrict__ S,
                                                 float* __restrict__ Hout,
                                                 int t0, int TC) {
    __shared__ unsigned int hp[2][2][16][72];   // [buf][hi/lo][m][72 dwords]
    const int b0   = blockIdx.x * 16;
    const int tid  = threadIdx.x;
    const int lane = tid & 63;
    const int wv   = tid >> 6;     // wave 0..7
    const int quad = lane >> 4;    // 0..3
    const int l15  = lane & 15;
    const int hu   = wv * 16 + l15;  // hidden unit owned by this lane

    // ---- static B-fragments: Whh[n][k], n = g*128 + hu ----
    h8 bh[4][4], bl[4][4];
#pragma unroll
    for (int g = 0; g < 4; ++g) {
        int n = g * 128 + hu;
#pragma unroll
        for (int q = 0; q < 4; ++q) {
            int kb = q * 32 + quad * 8;
            const float* wp = &Whh[(size_t)n * 128 + kb];
            float4 w0 = *(const float4*)wp;
            float4 w1 = *(const float4*)(wp + 4);
            float we[8] = {w0.x, w0.y, w0.z, w0.w, w1.x, w1.y, w1.z, w1.w};
#pragma unroll
            for (int j = 0; j < 8; ++j) {
                _Float16 hi = (_Float16)we[j];
                bh[g][q][j] = hi;
                bl[g][q][j] = (_Float16)(we[j] - (float)hi);
            }
        }
    }

    // ---- state init: c[r], h -> plane buf 0 ----
    float c[4];
#pragma unroll
    for (int r = 0; r < 4; ++r) {
        int m = quad * 4 + r;
        float h = S[(size_t)(b0 + m) * 128 + hu];
        c[r] = S[32768 + (size_t)(b0 + m) * 128 + hu];
        _Float16 hh = (_Float16)h;
        ((_Float16*)&hp[0][0][m][0])[hu] = hh;
        ((_Float16*)&hp[0][1][m][0])[hu] = (_Float16)(h - (float)hh);
    }
    lds_barrier();

    // ---- P element-offsets (invariant); base advances 512/step ----
    int off[4][4];
#pragma unroll
    for (int g = 0; g < 4; ++g)
#pragma unroll
        for (int r = 0; r < 4; ++r)
            off[g][r] = (b0 + quad * 4 + r) * TC * 512 + g * 128 + hu;

    float pc[4][4];
#pragma unroll
    for (int g = 0; g < 4; ++g)
#pragma unroll
        for (int r = 0; r < 4; ++r)
            pc[g][r] = P[off[g][r]];

    const bool wr = (Hout != nullptr);
    // Hout invariant offsets; uniform part (t0+tl)*128 advances per step
    const float* Pn = P + 512;              // prefetch base (tl+1)
    float* Ho = wr ? (Hout + (size_t)t0 * 128) : nullptr;

    for (int tl = 0; tl < TC; ++tl) {
        // prefetch next step's P (stays in flight across the lgkm barrier)
        float pn[4][4];
#pragma unroll
        for (int g = 0; g < 4; ++g)
#pragma unroll
            for (int r = 0; r < 4; ++r)
                pn[g][r] = Pn[off[g][r]];

        // A-fragments of h(t-1) from plane buf tl&1
        const int rb = tl & 1;
        h8 ah[4], al[4];
#pragma unroll
        for (int q = 0; q < 4; ++q) {
            int hoff = 32 * q + 8 * quad;
            ah[q] = *(const h8*)&((const _Float16*)&hp[rb][0][l15][0])[hoff];
            al[q] = *(const h8*)&((const _Float16*)&hp[rb][1][l15][0])[hoff];
        }

        // MFMA: acc[g] = P + h@W^T (fp16 hi/lo, 3 products)
        f32x4 acc[4];
#pragma unroll
        for (int g = 0; g < 4; ++g) {
            acc[g][0] = pc[g][0]; acc[g][1] = pc[g][1];
            acc[g][2] = pc[g][2]; acc[g][3] = pc[g][3];
        }
#pragma unroll
        for (int q = 0; q < 4; ++q) {
#pragma unroll
            for (int g = 0; g < 4; ++g) {
                acc[g] = __builtin_amdgcn_mfma_f32_16x16x32_f16(ah[q], bh[g][q], acc[g], 0, 0, 0);
                acc[g] = __builtin_amdgcn_mfma_f32_16x16x32_f16(al[q], bh[g][q], acc[g], 0, 0, 0);
                acc[g] = __builtin_amdgcn_mfma_f32_16x16x32_f16(ah[q], bl[g][q], acc[g], 0, 0, 0);
            }
        }

        // in-register activations; h -> plane buf (tl+1)&1
        const int wb = (tl + 1) & 1;
#pragma unroll
        for (int r = 0; r < 4; ++r) {
            int m = quad * 4 + r;
            float iv = fsigm(acc[0][r]);
            float fv = fsigm(acc[1][r]);
            float gv = ftanh(acc[2][r]);
            float ov = fsigm(acc[3][r]);
            c[r] = fv * c[r] + iv * gv;
            float h = ov * ftanh(c[r]);
            _Float16 hh = (_Float16)h;
            ((_Float16*)&hp[wb][0][m][0])[hu] = hh;
            ((_Float16*)&hp[wb][1][m][0])[hu] = (_Float16)(h - (float)hh);
            if (wr) Ho[((size_t)(b0 + m) * 512 + tl) * 128 + hu] = h;
            if (tl == TC - 1) {
                S[(size_t)(b0 + m) * 128 + hu] = h;
                S[32768 + (size_t)(b0 + m) * 128 + hu] = c[r];
            }
        }
        lds_barrier();

        Pn += 512;
#pragma unroll
        for (int g = 0; g < 4; ++g)
#pragma unroll
            for (int r = 0; r < 4; ++r)
                pc[g][r] = pn[g][r];
    }
}

// ---------------------------------------------------------------------------
// K7: tail head: out = tanh(tanh(h1_last) @ W2^T + b2) @ W3^T + b3
// ---------------------------------------------------------------------------
__global__ __launch_bounds__(64) void k_tail(const float* __restrict__ Hs,
                                             const float* __restrict__ W2,
                                             const float* __restrict__ b2,
                                             const float* __restrict__ W3,
                                             const float* __restrict__ b3,
                                             float* __restrict__ out) {
    __shared__ float last[128], l2s[64];
    const int b = blockIdx.x, tid = threadIdx.x;
    last[tid]      = ftanh(Hs[(size_t)b * 128 + tid]);
    last[tid + 64] = ftanh(Hs[(size_t)b * 128 + 64 + tid]);
    __syncthreads();
    float acc = b2[tid];
#pragma unroll 4
    for (int j = 0; j < 128; ++j) acc = fmaf(W2[(size_t)tid * 128 + j], last[j], acc);
    l2s[tid] = ftanh(acc);
    __syncthreads();
    if (tid < 32) {
        float a2 = b3[tid];
#pragma unroll 4
        for (int o = 0; o < 64; ++o) a2 = fmaf(W3[(size_t)tid * 64 + o], l2s[o], a2);
        out[(size_t)b * 32 + tid] = a2;
    }
}

// ---------------------------------------------------------------------------
extern "C" void kernel_launch(void* const* d_in, const int* in_sizes, int n_in,
                              void* d_out, int out_size, void* d_ws, size_t ws_size,
                              hipStream_t stream) {
    (void)in_sizes; (void)n_in; (void)out_size;
    const float* inp  = (const float*)d_in[0];
    const float* akey = (const float*)d_in[1];
    const float* aval = (const float*)d_in[2];
    const float* W1   = (const float*)d_in[3];
    const float* b1   = (const float*)d_in[4];
    const float* Wih0 = (const float*)d_in[5];
    const float* Whh0 = (const float*)d_in[6];
    const float* bih0 = (const float*)d_in[7];
    const float* bhh0 = (const float*)d_in[8];
    const float* Wih1 = (const float*)d_in[9];
    const float* Whh1 = (const float*)d_in[10];
    const float* bih1 = (const float*)d_in[11];
    const float* bhh1 = (const float*)d_in[12];
    const float* W2   = (const float*)d_in[13];
    const float* b2   = (const float*)d_in[14];
    const float* W3   = (const float*)d_in[15];
    const float* b3   = (const float*)d_in[16];

    float* ws   = (float*)d_ws;
    float* dist = ws;                       // 2,097,152
    float* hist = dist + 2097152;           //   139,264
    float* X    = hist + 139264;            // 8,388,608 + 64 pad
    float* S0   = X + 8388672;              //    65,536 (h then c)
    float* S1   = S0 + 65536;               //    65,536
    float* H0   = S1 + 65536;               // 16,777,216  (h0, [b][512][128])
    float* P0   = H0 + 16777216;            // 256*TC*512 + 1024
    const size_t fixed = (size_t)(P0 - ws);

    // per-TC floats: P0 + P1 = 2*(256*TC*512 + 1024)
    int TC = 32, tcs = 5;
    if ((fixed + 2ull * (131072ull * 128 + 1024)) * 4 <= ws_size)      { TC = 128; tcs = 7; }
    else if ((fixed + 2ull * (131072ull * 64 + 1024)) * 4 <= ws_size)  { TC = 64;  tcs = 6; }
    float* P1 = P0 + (size_t)256 * TC * 512 + 1024;

    k_dist<<<dim3(64, 4), 256, 0, stream>>>(inp, akey, dist);
    k_softmax<<<256, 256, 0, stream>>>(dist);
    hipMemsetAsync(hist, 0, 139264 * 4, stream);
    k_hist<<<dim3(9, 4, 8), 256, 0, stream>>>(dist, aval, hist);
    k_xfeat<<<dim3(4, 256), 256, 0, stream>>>(inp, hist, W1, b1, X);
    hipMemsetAsync(S0, 0, (size_t)2 * 65536 * 4, stream);  // S0+S1 contiguous
    for (int t0 = 0; t0 < 512; t0 += TC) {
        k_pregemm<64><<<dim3(4, 4 * TC), 256, 0, stream>>>(X, Wih0, bih0, bhh0, P0, t0, tcs);
        k_recM<<<16, 512, 0, stream>>>(P0, Whh0, S0, H0, t0, TC);
        k_pregemm<128><<<dim3(4, 4 * TC), 256, 0, stream>>>(H0, Wih1, bih1, bhh1, P1, t0, tcs);
        k_recM<<<16, 512, 0, stream>>>(P1, Whh1, S1, nullptr, t0, TC);
    }
    k_tail<<<256, 64, 0, stream>>>(S1, W2, b2, W3, b3, (float*)d_out);
}

// Round 7
// 1349.523 us; speedup vs baseline: 1.9254x; 1.6175x over previous
//
#include <hip/hip_runtime.h>

typedef _Float16 h8 __attribute__((ext_vector_type(8)));
typedef float f32x4 __attribute__((ext_vector_type(4)));

__device__ __forceinline__ float fsigm(float x) {
    return __builtin_amdgcn_rcpf(1.0f + __expf(-x));
}
__device__ __forceinline__ float ftanh(float x) {
    float ax = fabsf(x);
    float e  = __expf(-2.0f * ax);
    float r  = (1.0f - e) * __builtin_amdgcn_rcpf(1.0f + e);
    return copysignf(r, x);
}
// LDS-only barrier: drains lgkmcnt, leaves global loads/stores in flight.
__device__ __forceinline__ void lds_barrier() {
    asm volatile("s_waitcnt lgkmcnt(0)\n\ts_barrier" ::: "memory");
}

// ---------------------------------------------------------------------------
// K1: dist[256][8192] = input[256][512] @ akey[8192][512]^T   (NT GEMM, fp32)
// ---------------------------------------------------------------------------
__global__ __launch_bounds__(256) void k_dist(const float* __restrict__ A,
                                              const float* __restrict__ Bm,
                                              float* __restrict__ C) {
    __shared__ float As[32][68];
    __shared__ float Bs[32][132];
    const int n0 = blockIdx.x * 128;
    const int m0 = blockIdx.y * 64;
    const int tid = threadIdx.x;
    const int tx = tid & 15;
    const int ty = tid >> 4;
    const int lm = tid >> 3;
    const int lk = (tid & 7) * 4;
    float acc[4][8];
#pragma unroll
    for (int i = 0; i < 4; ++i)
#pragma unroll
        for (int j = 0; j < 8; ++j) acc[i][j] = 0.0f;

    for (int kt = 0; kt < 512; kt += 32) {
        __syncthreads();
#pragma unroll
        for (int r = 0; r < 2; ++r) {
            int m = lm + 32 * r;
            float4 v = *(const float4*)&A[(size_t)(m0 + m) * 512 + kt + lk];
            As[lk + 0][m] = v.x; As[lk + 1][m] = v.y;
            As[lk + 2][m] = v.z; As[lk + 3][m] = v.w;
        }
#pragma unroll
        for (int r = 0; r < 4; ++r) {
            int n = lm + 32 * r;
            float4 v = *(const float4*)&Bm[(size_t)(n0 + n) * 512 + kt + lk];
            Bs[lk + 0][n] = v.x; Bs[lk + 1][n] = v.y;
            Bs[lk + 2][n] = v.z; Bs[lk + 3][n] = v.w;
        }
        __syncthreads();
#pragma unroll
        for (int k = 0; k < 32; ++k) {
            float4 a4 = *(const float4*)&As[k][ty * 4];
            float4 b0 = *(const float4*)&Bs[k][tx * 8];
            float4 b1 = *(const float4*)&Bs[k][tx * 8 + 4];
            float av[4] = {a4.x, a4.y, a4.z, a4.w};
            float bv[8] = {b0.x, b0.y, b0.z, b0.w, b1.x, b1.y, b1.z, b1.w};
#pragma unroll
            for (int i = 0; i < 4; ++i)
#pragma unroll
                for (int j = 0; j < 8; ++j)
                    acc[i][j] = fmaf(av[i], bv[j], acc[i][j]);
        }
    }
#pragma unroll
    for (int i = 0; i < 4; ++i) {
        size_t row = (size_t)(m0 + ty * 4 + i) * 8192 + n0 + tx * 8;
        *(float4*)&C[row]     = make_float4(acc[i][0], acc[i][1], acc[i][2], acc[i][3]);
        *(float4*)&C[row + 4] = make_float4(acc[i][4], acc[i][5], acc[i][6], acc[i][7]);
    }
}

// ---------------------------------------------------------------------------
// K2: per-row argmax (first index on ties) -> set 0 -> softmax, in place
// ---------------------------------------------------------------------------
__global__ __launch_bounds__(256) void k_softmax(float* __restrict__ D) {
    __shared__ float row[8192];
    __shared__ float rv[256];
    __shared__ int   ri[256];
    const int b = blockIdx.x, tid = threadIdx.x;
    float* dr = D + (size_t)b * 8192;
    for (int i = tid; i < 2048; i += 256)
        *(float4*)&row[i * 4] = *(const float4*)&dr[i * 4];
    __syncthreads();

    float bv = -INFINITY; int bi = 0x7fffffff;
    for (int i = tid; i < 8192; i += 256) {
        float v = row[i];
        if (v > bv || (v == bv && i < bi)) { bv = v; bi = i; }
    }
    rv[tid] = bv; ri[tid] = bi;
    __syncthreads();
    for (int s = 128; s > 0; s >>= 1) {
        if (tid < s) {
            float ov = rv[tid + s]; int oi = ri[tid + s];
            if (ov > rv[tid] || (ov == rv[tid] && oi < ri[tid])) { rv[tid] = ov; ri[tid] = oi; }
        }
        __syncthreads();
    }
    if (tid == 0) row[ri[0]] = 0.0f;
    __syncthreads();

    float m = -INFINITY;
    for (int i = tid; i < 8192; i += 256) m = fmaxf(m, row[i]);
    rv[tid] = m;
    __syncthreads();
    for (int s = 128; s > 0; s >>= 1) {
        if (tid < s) rv[tid] = fmaxf(rv[tid], rv[tid + s]);
        __syncthreads();
    }
    const float M = rv[0];
    __syncthreads();

    float ssum = 0.0f;
    for (int i = tid; i < 8192; i += 256) {
        float e = __expf(row[i] - M);
        row[i] = e;
        ssum += e;
    }
    rv[tid] = ssum;
    __syncthreads();
    for (int s = 128; s > 0; s >>= 1) {
        if (tid < s) rv[tid] += rv[tid + s];
        __syncthreads();
    }
    const float inv = 1.0f / rv[0];
    for (int i = tid; i < 2048; i += 256) {
        float4 v = *(float4*)&row[i * 4];
        v.x *= inv; v.y *= inv; v.z *= inv; v.w *= inv;
        *(float4*)&dr[i * 4] = v;
    }
}

// ---------------------------------------------------------------------------
// K3: hist[256][544] += a[256][8192] @ aval[8192][544]  (NN GEMM, split-K=8)
// ---------------------------------------------------------------------------
__global__ __launch_bounds__(256) void k_hist(const float* __restrict__ A,
                                              const float* __restrict__ Bm,
                                              float* __restrict__ C) {
    __shared__ float As[32][68];
    __shared__ float Bs[32][68];
    const int n0 = blockIdx.x * 64;
    const int m0 = blockIdx.y * 64;
    const int kz = blockIdx.z;
    const int tid = threadIdx.x;
    const int tx = tid & 15, ty = tid >> 4;
    const int lr = tid >> 3;
    const int lq = (tid & 7) * 4;
    float acc[4][4];
#pragma unroll
    for (int i = 0; i < 4; ++i)
#pragma unroll
        for (int j = 0; j < 4; ++j) acc[i][j] = 0.0f;

    const int k_lo = kz * 1024, k_hi = k_lo + 1024;
    for (int kt = k_lo; kt < k_hi; kt += 32) {
        __syncthreads();
#pragma unroll
        for (int r = 0; r < 2; ++r) {
            int m = lr + 32 * r;
            float4 v = *(const float4*)&A[(size_t)(m0 + m) * 8192 + kt + lq];
            As[lq + 0][m] = v.x; As[lq + 1][m] = v.y;
            As[lq + 2][m] = v.z; As[lq + 3][m] = v.w;
        }
#pragma unroll
        for (int r = 0; r < 2; ++r) {
            int kk = (tid >> 4) + 16 * r;
            int nq = (tid & 15) * 4;
            float4 v = make_float4(0.f, 0.f, 0.f, 0.f);
            if (n0 + nq < 544)
                v = *(const float4*)&Bm[(size_t)(kt + kk) * 544 + n0 + nq];
            *(float4*)&Bs[kk][nq] = v;
        }
        __syncthreads();
#pragma unroll
        for (int k = 0; k < 32; ++k) {
            float4 a4 = *(const float4*)&As[k][ty * 4];
            float4 b4 = *(const float4*)&Bs[k][tx * 4];
            float av[4] = {a4.x, a4.y, a4.z, a4.w};
            float bv[4] = {b4.x, b4.y, b4.z, b4.w};
#pragma unroll
            for (int i = 0; i < 4; ++i)
#pragma unroll
                for (int j = 0; j < 4; ++j)
                    acc[i][j] = fmaf(av[i], bv[j], acc[i][j]);
        }
    }
#pragma unroll
    for (int i = 0; i < 4; ++i)
#pragma unroll
        for (int j = 0; j < 4; ++j) {
            int n = n0 + tx * 4 + j;
            if (n < 544)
                atomicAdd(&C[(size_t)(m0 + ty * 4 + i) * 544 + n], acc[i][j]);
        }
}

// ---------------------------------------------------------------------------
// K4: x[b][t][o] = tanh(b1[o] + W1[o][0]*input[b][t] + sum_j W1[o][1+j]*hist[b][t+j])
// ---------------------------------------------------------------------------
__global__ __launch_bounds__(256) void k_xfeat(const float* __restrict__ inp,
                                               const float* __restrict__ hist,
                                               const float* __restrict__ W1,
                                               const float* __restrict__ b1,
                                               float* __restrict__ X) {
    __shared__ float w[33 * 64];
    __shared__ float bl[64];
    __shared__ float il[128];
    __shared__ float hl[160];
    const int t0 = blockIdx.x * 128;
    const int b  = blockIdx.y;
    const int tid = threadIdx.x;
    for (int idx = tid; idx < 2112; idx += 256) {
        int o = idx / 33, k = idx % 33;
        w[k * 64 + o] = W1[idx];
    }
    if (tid < 64) bl[tid] = b1[tid];
    if (tid < 128) il[tid] = inp[(size_t)b * 512 + t0 + tid];
    for (int i = tid; i < 159; i += 256) hl[i] = hist[(size_t)b * 544 + t0 + i];
    __syncthreads();
    const int o = tid & 63, tq = tid >> 6;
    for (int it = 0; it < 32; ++it) {
        int tl = it * 4 + tq;
        float acc = fmaf(il[tl], w[o], bl[o]);
#pragma unroll
        for (int j = 0; j < 32; ++j)
            acc = fmaf(hl[tl + j], w[(1 + j) * 64 + o], acc);
        X[(size_t)(b * 512 + t0 + tl) * 64 + o] = ftanh(acc);
    }
}

// ---------------------------------------------------------------------------
// Device body: pre-gate GEMM, 512 threads, tile 64(m) x 128(n) x 32(k).
// P[m][g] = bih[g]+bhh[g] + A[row(m)][:K] . W[g][:K]; row(m) via (tcs, t0).
// ---------------------------------------------------------------------------
template <int K>
__device__ __forceinline__ void pregemm_body(const float* __restrict__ A,
                                             const float* __restrict__ Bw,
                                             const float* __restrict__ bih,
                                             const float* __restrict__ bhh,
                                             float* __restrict__ C,
                                             int t0, int tcs, int gb, float* sm) {
    float* As = sm;             // [32][68]
    float* Bs = sm + 32 * 68;   // [32][132]
    const int n0 = (gb & 3) * 128;
    const int m0 = (gb >> 2) * 64;
    const int tid = threadIdx.x;
    const int tx = tid & 31;      // n/4
    const int ty = tid >> 5;      // m/4
    const int lm = tid >> 3;      // 0..63
    const int lk = (tid & 7) * 4; // 0..28
    const int ln = tid >> 2;      // 0..127
    const int lkb = (tid & 3) * 8;
    const int tcm = (1 << tcs) - 1;
    float acc[4][4];
#pragma unroll
    for (int i = 0; i < 4; ++i)
#pragma unroll
        for (int j = 0; j < 4; ++j) acc[i][j] = 0.0f;

    for (int kt = 0; kt < K; kt += 32) {
        __syncthreads();
        {
            int m = m0 + lm;
            size_t arow = (size_t)(m >> tcs) * 512 + t0 + (m & tcm);
            float4 v = *(const float4*)&A[arow * K + kt + lk];
            As[(lk + 0) * 68 + lm] = v.x; As[(lk + 1) * 68 + lm] = v.y;
            As[(lk + 2) * 68 + lm] = v.z; As[(lk + 3) * 68 + lm] = v.w;
        }
        {
            const float* bp = &Bw[(size_t)(n0 + ln) * K + kt + lkb];
            float4 v0 = *(const float4*)bp;
            float4 v1 = *(const float4*)(bp + 4);
            Bs[(lkb + 0) * 132 + ln] = v0.x; Bs[(lkb + 1) * 132 + ln] = v0.y;
            Bs[(lkb + 2) * 132 + ln] = v0.z; Bs[(lkb + 3) * 132 + ln] = v0.w;
            Bs[(lkb + 4) * 132 + ln] = v1.x; Bs[(lkb + 5) * 132 + ln] = v1.y;
            Bs[(lkb + 6) * 132 + ln] = v1.z; Bs[(lkb + 7) * 132 + ln] = v1.w;
        }
        __syncthreads();
#pragma unroll
        for (int k = 0; k < 32; ++k) {
            float4 a4 = *(const float4*)&As[k * 68 + ty * 4];
            float4 b4 = *(const float4*)&Bs[k * 132 + tx * 4];
            float av[4] = {a4.x, a4.y, a4.z, a4.w};
            float bv[4] = {b4.x, b4.y, b4.z, b4.w};
#pragma unroll
            for (int i = 0; i < 4; ++i)
#pragma unroll
                for (int j = 0; j < 4; ++j)
                    acc[i][j] = fmaf(av[i], bv[j], acc[i][j]);
        }
    }
    float bb[4];
#pragma unroll
    for (int j = 0; j < 4; ++j) {
        int n = n0 + tx * 4 + j;
        bb[j] = bih[n] + bhh[n];
    }
#pragma unroll
    for (int i = 0; i < 4; ++i) {
        size_t row = (size_t)(m0 + ty * 4 + i) * 512 + n0 + tx * 4;
        *(float4*)&C[row] = make_float4(acc[i][0] + bb[0], acc[i][1] + bb[1],
                                        acc[i][2] + bb[2], acc[i][3] + bb[3]);
    }
}

// ---------------------------------------------------------------------------
// Device body: MFMA LSTM recurrence over one t-chunk (as round 6, lane-local
// gates, double-buffered fp16 hi/lo h planes, one lgkm-only barrier/step).
// ---------------------------------------------------------------------------
__device__ __forceinline__ void rec_body(const float* __restrict__ P,
                                         const float* __restrict__ Whh,
                                         float* __restrict__ S,
                                         float* __restrict__ Hout,
                                         int t0, int TC, int blk, float* sm) {
    unsigned int* hpb = (unsigned int*)sm;   // [buf][pl][16][72] dwords
#define HPROW(buf, pl, m) ((_Float16*)(hpb + ((((buf)*2 + (pl))*16 + (m)) * 72)))
    const int b0   = blk * 16;
    const int tid  = threadIdx.x;
    const int lane = tid & 63;
    const int wv   = tid >> 6;
    const int quad = lane >> 4;
    const int l15  = lane & 15;
    const int hu   = wv * 16 + l15;

    h8 bh[4][4], bl[4][4];
#pragma unroll
    for (int g = 0; g < 4; ++g) {
        int n = g * 128 + hu;
#pragma unroll
        for (int q = 0; q < 4; ++q) {
            int kb = q * 32 + quad * 8;
            const float* wp = &Whh[(size_t)n * 128 + kb];
            float4 w0 = *(const float4*)wp;
            float4 w1 = *(const float4*)(wp + 4);
            float we[8] = {w0.x, w0.y, w0.z, w0.w, w1.x, w1.y, w1.z, w1.w};
#pragma unroll
            for (int j = 0; j < 8; ++j) {
                _Float16 hi = (_Float16)we[j];
                bh[g][q][j] = hi;
                bl[g][q][j] = (_Float16)(we[j] - (float)hi);
            }
        }
    }

    float c[4];
#pragma unroll
    for (int r = 0; r < 4; ++r) {
        int m = quad * 4 + r;
        float h = S[(size_t)(b0 + m) * 128 + hu];
        c[r] = S[32768 + (size_t)(b0 + m) * 128 + hu];
        _Float16 hh = (_Float16)h;
        HPROW(0, 0, m)[hu] = hh;
        HPROW(0, 1, m)[hu] = (_Float16)(h - (float)hh);
    }
    lds_barrier();

    int off[4][4];
#pragma unroll
    for (int g = 0; g < 4; ++g)
#pragma unroll
        for (int r = 0; r < 4; ++r)
            off[g][r] = (b0 + quad * 4 + r) * TC * 512 + g * 128 + hu;

    float pc[4][4];
#pragma unroll
    for (int g = 0; g < 4; ++g)
#pragma unroll
        for (int r = 0; r < 4; ++r)
            pc[g][r] = P[off[g][r]];

    const bool wr = (Hout != nullptr);
    const float* Pn = P + 512;
    float* Ho = wr ? (Hout + (size_t)t0 * 128) : nullptr;

    for (int tl = 0; tl < TC; ++tl) {
        float pn[4][4];
#pragma unroll
        for (int g = 0; g < 4; ++g)
#pragma unroll
            for (int r = 0; r < 4; ++r)
                pn[g][r] = Pn[off[g][r]];

        const int rb = tl & 1;
        h8 ah[4], al[4];
#pragma unroll
        for (int q = 0; q < 4; ++q) {
            int hoff = 32 * q + 8 * quad;
            ah[q] = *(const h8*)&HPROW(rb, 0, l15)[hoff];
            al[q] = *(const h8*)&HPROW(rb, 1, l15)[hoff];
        }

        f32x4 acc[4];
#pragma unroll
        for (int g = 0; g < 4; ++g) {
            acc[g][0] = pc[g][0]; acc[g][1] = pc[g][1];
            acc[g][2] = pc[g][2]; acc[g][3] = pc[g][3];
        }
#pragma unroll
        for (int q = 0; q < 4; ++q) {
#pragma unroll
            for (int g = 0; g < 4; ++g) {
                acc[g] = __builtin_amdgcn_mfma_f32_16x16x32_f16(ah[q], bh[g][q], acc[g], 0, 0, 0);
                acc[g] = __builtin_amdgcn_mfma_f32_16x16x32_f16(al[q], bh[g][q], acc[g], 0, 0, 0);
                acc[g] = __builtin_amdgcn_mfma_f32_16x16x32_f16(ah[q], bl[g][q], acc[g], 0, 0, 0);
            }
        }

        const int wb = (tl + 1) & 1;
#pragma unroll
        for (int r = 0; r < 4; ++r) {
            int m = quad * 4 + r;
            float iv = fsigm(acc[0][r]);
            float fv = fsigm(acc[1][r]);
            float gv = ftanh(acc[2][r]);
            float ov = fsigm(acc[3][r]);
            c[r] = fv * c[r] + iv * gv;
            float h = ov * ftanh(c[r]);
            _Float16 hh = (_Float16)h;
            HPROW(wb, 0, m)[hu] = hh;
            HPROW(wb, 1, m)[hu] = (_Float16)(h - (float)hh);
            if (wr) Ho[((size_t)(b0 + m) * 512 + tl) * 128 + hu] = h;
            if (tl == TC - 1) {
                S[(size_t)(b0 + m) * 128 + hu] = h;
                S[32768 + (size_t)(b0 + m) * 128 + hu] = c[r];
            }
        }
        lds_barrier();

        Pn += 512;
#pragma unroll
        for (int g = 0; g < 4; ++g)
#pragma unroll
            for (int r = 0; r < 4; ++r)
                pc[g][r] = pn[g][r];
    }
#undef HPROW
}

// ---------------------------------------------------------------------------
// K5: fused pipeline stage. Blocks 0-15: layer0 recurrence chunk k.
// Blocks 16-31: layer1 recurrence chunk k-2. Blocks 32..32+16TC-1: pre-gate
// GEMM layer0 chunk k+1. Rest: pre-gate GEMM layer1 chunk k-1. All four are
// mutually independent; launch boundaries provide the producer->consumer
// ordering (P0/P1 double-buffered).
// ---------------------------------------------------------------------------
__global__ __launch_bounds__(512, 2) void k_fused(
        const float* __restrict__ X,    const float* __restrict__ H0,
        const float* __restrict__ Wih0, const float* __restrict__ Wih1,
        const float* __restrict__ bih0, const float* __restrict__ bhh0,
        const float* __restrict__ bih1, const float* __restrict__ bhh1,
        const float* __restrict__ Whh0, const float* __restrict__ Whh1,
        const float* __restrict__ P0r, float* __restrict__ P0w,
        const float* __restrict__ P1r, float* __restrict__ P1w,
        float* __restrict__ S0, float* __restrict__ S1, float* __restrict__ H0out,
        int tr0, int tr1, int tp0, int tp1,
        int v_rec0, int v_rec1, int v_pre0, int v_pre1,
        int TC, int tcs) {
    __shared__ float smem[6400];   // 25.6 KB: max(rec 18.4 KB, gemm 25.6 KB)
    const int bid = blockIdx.x;
    if (bid < 16) {
        if (v_rec0) rec_body(P0r, Whh0, S0, H0out, tr0, TC, bid, smem);
        return;
    }
    if (bid < 32) {
        if (v_rec1) rec_body(P1r, Whh1, S1, nullptr, tr1, TC, bid - 16, smem);
        return;
    }
    int gb = bid - 32;
    const int npre = 16 * TC;
    if (gb < npre) {
        if (v_pre0) pregemm_body<64>(X, Wih0, bih0, bhh0, P0w, tp0, tcs, gb, smem);
        return;
    }
    gb -= npre;
    if (v_pre1) pregemm_body<128>(H0, Wih1, bih1, bhh1, P1w, tp1, tcs, gb, smem);
}

// ---------------------------------------------------------------------------
// K6: tail head: out = tanh(tanh(h1_last) @ W2^T + b2) @ W3^T + b3
// ---------------------------------------------------------------------------
__global__ __launch_bounds__(64) void k_tail(const float* __restrict__ Hs,
                                             const float* __restrict__ W2,
                                             const float* __restrict__ b2,
                                             const float* __restrict__ W3,
                                             const float* __restrict__ b3,
                                             float* __restrict__ out) {
    __shared__ float last[128], l2s[64];
    const int b = blockIdx.x, tid = threadIdx.x;
    last[tid]      = ftanh(Hs[(size_t)b * 128 + tid]);
    last[tid + 64] = ftanh(Hs[(size_t)b * 128 + 64 + tid]);
    __syncthreads();
    float acc = b2[tid];
#pragma unroll 4
    for (int j = 0; j < 128; ++j) acc = fmaf(W2[(size_t)tid * 128 + j], last[j], acc);
    l2s[tid] = ftanh(acc);
    __syncthreads();
    if (tid < 32) {
        float a2 = b3[tid];
#pragma unroll 4
        for (int o = 0; o < 64; ++o) a2 = fmaf(W3[(size_t)tid * 64 + o], l2s[o], a2);
        out[(size_t)b * 32 + tid] = a2;
    }
}

// ---------------------------------------------------------------------------
extern "C" void kernel_launch(void* const* d_in, const int* in_sizes, int n_in,
                              void* d_out, int out_size, void* d_ws, size_t ws_size,
                              hipStream_t stream) {
    (void)in_sizes; (void)n_in; (void)out_size;
    const float* inp  = (const float*)d_in[0];
    const float* akey = (const float*)d_in[1];
    const float* aval = (const float*)d_in[2];
    const float* W1   = (const float*)d_in[3];
    const float* b1   = (const float*)d_in[4];
    const float* Wih0 = (const float*)d_in[5];
    const float* Whh0 = (const float*)d_in[6];
    const float* bih0 = (const float*)d_in[7];
    const float* bhh0 = (const float*)d_in[8];
    const float* Wih1 = (const float*)d_in[9];
    const float* Whh1 = (const float*)d_in[10];
    const float* bih1 = (const float*)d_in[11];
    const float* bhh1 = (const float*)d_in[12];
    const float* W2   = (const float*)d_in[13];
    const float* b2   = (const float*)d_in[14];
    const float* W3   = (const float*)d_in[15];
    const float* b3   = (const float*)d_in[16];

    float* ws   = (float*)d_ws;
    float* dist = ws;                       // 2,097,152
    float* hist = dist + 2097152;           //   139,264
    float* X    = hist + 139264;            // 8,388,608 + 64 pad
    float* S0   = X + 8388672;              //    65,536 (h then c)
    float* S1   = S0 + 65536;               //    65,536
    float* H0   = S1 + 65536;               // 16,777,216  (h0, [b][512][128])
    float* PB   = H0 + 16777216;            // 4 P buffers
    const size_t fixed = (size_t)(PB - ws);

    // 4 P buffers of 256*TC*512 + 512 floats (P0 x2, P1 x2 ping-pong)
    int TC = 16, tcs = 4;
    if ((fixed + 4ull * (8388608ull + 512)) * 4 <= ws_size)      { TC = 64; tcs = 6; }
    else if ((fixed + 4ull * (4194304ull + 512)) * 4 <= ws_size) { TC = 32; tcs = 5; }
    const size_t pchunk = (size_t)256 * TC * 512 + 512;
    float* P0b[2] = {PB, PB + pchunk};
    float* P1b[2] = {PB + 2 * pchunk, PB + 3 * pchunk};

    k_dist<<<dim3(64, 4), 256, 0, stream>>>(inp, akey, dist);
    k_softmax<<<256, 256, 0, stream>>>(dist);
    hipMemsetAsync(hist, 0, 139264 * 4, stream);
    k_hist<<<dim3(9, 4, 8), 256, 0, stream>>>(dist, aval, hist);
    k_xfeat<<<dim3(4, 256), 256, 0, stream>>>(inp, hist, W1, b1, X);
    hipMemsetAsync(S0, 0, (size_t)2 * 65536 * 4, stream);  // S0+S1 contiguous

    const int NC = 512 / TC;
    const int nblocks = 32 + 32 * TC;   // 32 rec + 16*TC pre0 + 16*TC pre1
    for (int k = -1; k <= NC + 1; ++k) {
        int v_rec0 = (k >= 0 && k < NC);
        int v_rec1 = (k >= 2 && k < NC + 2);
        int v_pre0 = (k + 1 >= 0 && k + 1 < NC);
        int v_pre1 = (k - 1 >= 0 && k - 1 < NC);
        if (!(v_rec0 | v_rec1 | v_pre0 | v_pre1)) continue;
        const float* P0r = P0b[k & 1];
        float*       P0w = P0b[(k + 1) & 1];
        const float* P1r = P1b[k & 1];          // chunk k-2 parity == k parity
        float*       P1w = P1b[(k + 1) & 1];    // chunk k-1 parity == k+1 parity
        k_fused<<<nblocks, 512, 0, stream>>>(
            X, H0, Wih0, Wih1, bih0, bhh0, bih1, bhh1, Whh0, Whh1,
            P0r, P0w, P1r, P1w, S0, S1, H0,
            k * TC, (k - 2) * TC, (k + 1) * TC, (k - 1) * TC,
            v_rec0, v_rec1, v_pre0, v_pre1, TC, tcs);
    }
    k_tail<<<256, 64, 0, stream>>>(S1, W2, b2, W3, b3, (float*)d_out);
}